// Round 17
// baseline (271.114 us; speedup 1.0000x reference)
//
#include <hip/hip_runtime.h>
#include <math.h>

#define PX 4096   // 64*64
#define TT 32
#define DD 32
#define CC 64     // 2*D
#define PW 66     // padded width
#define PPX 4356  // 66*66

typedef __attribute__((ext_vector_type(8))) short short8v;
typedef __attribute__((ext_vector_type(4))) float f32x4;

__device__ __forceinline__ float gelu_fast(float x) {
    float u = x * x;
    float a = x * (1.5957691216057308f + 0.07135481627f * u);
    return x / (1.0f + __expf(-a));
}

__device__ __forceinline__ unsigned short f2b(float x) {
    union { float f; unsigned u; } v; v.f = x;
    unsigned r = v.u + 0x7FFF + ((v.u >> 16) & 1);
    return (unsigned short)(r >> 16);
}

__device__ __forceinline__ float b2f(unsigned short b) {
    union { unsigned u; float f; } v; v.u = ((unsigned)b) << 16;
    return v.f;
}

// ---------------- K1: LN1 (64ch) fused -> padded bf16 NHWC ------------------
__global__ __launch_bounds__(256) void k1_ln1(
        const float* __restrict__ xre, const float* __restrict__ xim,
        const float* __restrict__ g, const float* __restrict__ b,
        unsigned short* __restrict__ xpad) {
    int gid = blockIdx.x * 256 + threadIdx.x;   // t*4096 + px
    int t = gid >> 12, px = gid & 4095;
    int row = px >> 6, col = px & 63;
    const float* pr = xre + (size_t)t * DD * PX + px;
    const float* pi = xim + (size_t)t * DD * PX + px;
    float s = 0.f, ss = 0.f;
    #pragma unroll
    for (int d = 0; d < DD; ++d) {
        float vr = pr[d * PX], vi = pi[d * PX];
        s += vr + vi; ss += vr * vr + vi * vi;
    }
    float m = s * (1.f / 64.f);
    float var = ss * (1.f / 64.f) - m * m;
    float rs = rsqrtf(var + 1e-5f);
    unsigned short* o = xpad + ((size_t)t * PPX + (row + 1) * PW + (col + 1)) * 64;
    #pragma unroll
    for (int j = 0; j < 8; ++j) {
        short8v v8;
        #pragma unroll
        for (int dd = 0; dd < 8; ++dd) {
            int ch = j * 8 + dd;
            float v = (ch < 32) ? (pr[ch * PX] - m) * rs * g[ch] + b[ch]
                                : (pi[(ch - 32) * PX] - m) * rs * g[ch] + b[ch];
            v8[dd] = (short)f2b(v);
        }
        *(short8v*)&o[j * 8] = v8;
    }
}

// ---------------- KZ: zero the halo of xpad ---------------------------------
__global__ __launch_bounds__(256) void kz_halo(unsigned short* __restrict__ xpad) {
    int gid = blockIdx.x * 256 + threadIdx.x;
    if (gid >= 32 * 260) return;
    int im = gid / 260, h = gid % 260;
    int row, col;
    if (h < 66)       { row = 0;  col = h; }
    else if (h < 132) { row = 65; col = h - 66; }
    else { int hh = h - 132; row = 1 + (hh >> 1); col = (hh & 1) * 65; }
    unsigned short* p = xpad + ((size_t)im * PPX + row * PW + col) * 64;
    short8v z = (short8v)0;
    #pragma unroll
    for (int j = 0; j < 8; ++j) *(short8v*)&p[j * 8] = z;
}

// ---------------- K0: prep — bf16/transpose/swizzle all weight matrices -----
__global__ __launch_bounds__(256) void k0_prep(
        const float* __restrict__ w1, const float* __restrict__ w2,
        const float* __restrict__ convw,
        const float* __restrict__ encre, const float* __restrict__ encim,
        const float* __restrict__ decre, const float* __restrict__ decim,
        unsigned short* __restrict__ w1t, unsigned short* __restrict__ w2t,
        unsigned short* __restrict__ w9t,
        unsigned short* __restrict__ benct, unsigned short* __restrict__ bdect) {
    int gid = blockIdx.x * 256 + threadIdx.x;
    if (gid < 32768) {
        int idx = gid;
        int e = idx >> 13, r = idx & 8191;
        int f = r >> 6, p = r & 63;
        int c = (p & 7) + 8 * ((p >> 3) ^ (f & 7));
        w1t[idx] = f2b(w1[((size_t)e * 64 + c) * 128 + f]);
    } else if (gid < 65536) {
        int idx = gid - 32768;
        int e = idx >> 13, r = idx & 8191;
        int n = r >> 7, p = r & 127;
        int f = (p & 7) + 8 * ((p >> 3) ^ (n & 7));
        w2t[idx] = f2b(w2[((size_t)e * 128 + f) * 64 + n]);
    } else if (gid < 102400) {
        int idx = gid - 65536;
        int tap = idx >> 12, rem = idx & 4095;
        int n = rem >> 6, p = rem & 63;
        int k = (p & 7) + 8 * ((p >> 3) ^ (n & 7));
        w9t[idx] = f2b(convw[((size_t)n * 64 + k) * 9 + tap]);
    } else if (gid < 110592) {
        int idx = gid - 102400;
        const float* Rr = (idx < 4096) ? encre : decre;
        const float* Ri = (idx < 4096) ? encim : decim;
        unsigned short* dst = (idx < 4096) ? benct : bdect;
        idx &= 4095;
        int n = idx >> 6, p = idx & 63;
        int k = (p & 7) + 8 * ((p >> 3) ^ (n & 7));
        float v;
        if (n < 32) v = (k < 32) ? Rr[k * 32 + n] : -Ri[(k - 32) * 32 + n];
        else        v = (k < 32) ? Ri[k * 32 + (n - 32)] : Rr[(k - 32) * 32 + (n - 32)];
        dst[idx] = f2b(v);
    }
}

// ---------------- K2: 3x3 conv 64->64 as 9-tap implicit GEMM (bf16 MFMA) ----
// Output now bf16 NHWC (halves store traffic; k5a re-rounds to bf16 anyway).
__global__ __launch_bounds__(256, 2) void k2_conv(
        const unsigned short* __restrict__ xpad,
        const unsigned short* __restrict__ w9t,
        const float* __restrict__ bias, unsigned short* __restrict__ xsb) {
    __shared__ __align__(16) unsigned short wst[36864];   // 9 taps x 64oc x 64ic swz
    int tid = threadIdx.x;
    int bid = blockIdx.x;
    int lb = (bid & 7) * 64 + (bid >> 3);   // bijective (512 % 8 == 0)
    int t = lb >> 4, rg = lb & 15;
    int lane = tid & 63, wv = tid >> 6;
    int l15 = lane & 15, g = lane >> 4;
    #pragma unroll
    for (int i = 0; i < 18; ++i) {
        int idx = i * 256 + tid;
        *(short8v*)&wst[idx * 8] = *(const short8v*)&w9t[idx * 8];
    }
    __syncthreads();
    int r = rg * 4 + wv;
    const unsigned short* xb = xpad + (size_t)t * PPX * 64;
    f32x4 acc[4][4];
    #pragma unroll
    for (int m = 0; m < 4; ++m)
        #pragma unroll
        for (int nt = 0; nt < 4; ++nt) acc[m][nt] = (f32x4)0.f;

    #pragma unroll
    for (int kh = 0; kh < 3; ++kh) {
        #pragma unroll
        for (int kw = 0; kw < 3; ++kw) {
            int tap = kh * 3 + kw;
            #pragma unroll
            for (int kc = 0; kc < 2; ++kc) {
                short8v a[4];
                #pragma unroll
                for (int m = 0; m < 4; ++m) {
                    int pcol = m * 16 + l15 + kw;
                    a[m] = *(const short8v*)&xb[((size_t)(r + kh) * PW + pcol) * 64 + kc * 32 + g * 8];
                }
                #pragma unroll
                for (int nt = 0; nt < 4; ++nt) {
                    int n = nt * 16 + l15;
                    short8v bf = *(const short8v*)&wst[tap * 4096 + n * 64 + ((kc * 4 + g) ^ (n & 7)) * 8];
                    #pragma unroll
                    for (int m = 0; m < 4; ++m)
                        acc[m][nt] = __builtin_amdgcn_mfma_f32_16x16x32_bf16(a[m], bf, acc[m][nt], 0, 0, 0);
                }
            }
        }
    }
    unsigned short* dst = xsb + ((size_t)t * PX + r * 64) * 64;
    #pragma unroll
    for (int nt = 0; nt < 4; ++nt) {
        float bo = bias[nt * 16 + l15];
        #pragma unroll
        for (int m = 0; m < 4; ++m) {
            #pragma unroll
            for (int reg = 0; reg < 4; ++reg) {
                int tok = m * 16 + g * 4 + reg;
                dst[(size_t)tok * 64 + nt * 16 + l15] = f2b(acc[m][nt][reg] + bo);
            }
        }
    }
}

// ---------------- K3: per-(t,c) spatial mean (bf16 NHWC input) --------------
__global__ __launch_bounds__(256) void k3_mean(
        const unsigned short* __restrict__ xsb, float* __restrict__ mean) {
    __shared__ f32x4 red[256];
    int t = blockIdx.x;
    int c4 = threadIdx.x & 15, q = threadIdx.x >> 4;
    const unsigned short* base = xsb + (size_t)t * PX * 64 + c4 * 4;
    f32x4 s = (f32x4)0.f;
    for (int px = q; px < PX; px += 16) {
        uint2 v = *(const uint2*)&base[(size_t)px * 64];
        s[0] += b2f((unsigned short)(v.x & 0xffff));
        s[1] += b2f((unsigned short)(v.x >> 16));
        s[2] += b2f((unsigned short)(v.y & 0xffff));
        s[3] += b2f((unsigned short)(v.y >> 16));
    }
    red[threadIdx.x] = s;
    __syncthreads();
    for (int st = 8; st > 0; st >>= 1) {
        if (q < st) red[q * 16 + c4] += red[(q + st) * 16 + c4];
        __syncthreads();
    }
    if (q == 0) {
        f32x4 v = red[c4] * (1.f / 4096.f);
        *(f32x4*)&mean[t * 64 + c4 * 4] = v;
    }
}

// ---------------- K4: decay/forcing tables + flux scan ----------------------
__global__ __launch_bounds__(256) void k4_ops(
        const float* __restrict__ dt, const float* __restrict__ lam_re,
        const float* __restrict__ lam_im, const float* __restrict__ alpha,
        const float* __restrict__ wre, const float* __restrict__ wim,
        const float* __restrict__ mean, float* __restrict__ tabs,
        float* __restrict__ outflux) {
    int tid = threadIdx.x;
    for (int idx = tid; idx < 1024; idx += 256) {
        int t = idx >> 5, d = idx & 31;
        float x = lam_re[d];
        float sp = (x > 0.f) ? x + log1pf(expf(-x)) : log1pf(expf(x));
        float lr = -sp, li = lam_im[d];
        float dtv = dt[t];
        float er = expf(lr * dtv);
        float dr = er * cosf(li * dtv);
        float di = er * sinf(li * dtv);
        float den = lr * lr + li * li;
        float fr = ((dr - 1.f) * lr + di * li) / den;
        float fi = (di * lr - (dr - 1.f) * li) / den;
        tabs[idx] = dr; tabs[1024 + idx] = di;
        tabs[2048 + idx] = fr; tabs[3072 + idx] = fi;
    }
    if (tid < 32) {
        int d = tid;
        float a = 1.f / (1.f + expf(-alpha[d]));
        float yr = 0.f, yi = 0.f;
        for (int t = 0; t < 32; ++t) {
            float xr = 0.f, xi = 0.f;
            for (int k = 0; k < 32; ++k) {
                float mr = mean[t * 64 + k], mi = mean[t * 64 + 32 + k];
                float wr = wre[k * 32 + d], wi = wim[k * 32 + d];
                xr += mr * wr - mi * wi;
                xi += mr * wi + mi * wr;
            }
            yr = a * yr + xr; yi = a * yi + xi;
        }
        outflux[d] = yr; outflux[32 + d] = yi;
    }
}

// ---------------- K5a: enc GEMM (bf16 A) + forcing, 2 tiles per block -------
__global__ __launch_bounds__(256) void k5a_enc(
        const unsigned short* __restrict__ Ab, const unsigned short* __restrict__ Bt,
        const float* __restrict__ tabs, float* __restrict__ O) {
    __shared__ __align__(16) unsigned short fA[64 * 64];
    __shared__ __align__(16) unsigned short bst[64 * 64];
    int tid = threadIdx.x;
    int lane = tid & 63, wv = tid >> 6;
    int l15 = lane & 15, g = lane >> 4;
    int row0 = wv * 16 + l15;
    int rowb = wv * 16 + g * 4;
    #pragma unroll
    for (int i = 0; i < 2; ++i)
        *(short8v*)&bst[(i * 256 + tid) * 8] = *(const short8v*)&Bt[(i * 256 + tid) * 8];

    #pragma unroll
    for (int tile = 0; tile < 2; ++tile) {
        size_t tok0 = ((size_t)blockIdx.x * 2 + tile) * 64;
        if (tile) __syncthreads();   // prev tile's fA fragment reads done
        // bf16 source: 8-wide chunk copies with XOR swizzle (512 chunks)
        #pragma unroll
        for (int i = 0; i < 2; ++i) {
            int idx = i * 256 + tid;
            int tok = idx >> 3, cc = idx & 7;
            *(short8v*)&fA[tok * 64 + (cc ^ (tok & 7)) * 8] =
                *(const short8v*)&Ab[(tok0 + tok) * 64 + cc * 8];
        }
        __syncthreads();
        short8v a1[2];
        #pragma unroll
        for (int st = 0; st < 2; ++st)
            a1[st] = *(const short8v*)&fA[row0 * 64 + (((st * 4 + g) ^ (row0 & 7))) * 8];
        f32x4 eo[4];
        #pragma unroll
        for (int i = 0; i < 4; ++i) eo[i] = (f32x4)0.f;
        #pragma unroll
        for (int st = 0; st < 2; ++st) {
            #pragma unroll
            for (int nt = 0; nt < 4; ++nt) {
                int n = nt * 16 + l15;
                short8v b = *(const short8v*)&bst[n * 64 + (((st * 4 + g) ^ (n & 7))) * 8];
                eo[nt] = __builtin_amdgcn_mfma_f32_16x16x32_bf16(a1[st], b, eo[nt], 0, 0, 0);
            }
        }
        {
            int t = (int)(tok0 >> 12);
            #pragma unroll
            for (int p = 0; p < 2; ++p) {
                int d = p * 16 + l15;
                float fr = tabs[2048 + t * 32 + d], fi = tabs[3072 + t * 32 + d];
                #pragma unroll
                for (int r = 0; r < 4; ++r) {
                    float ur = eo[p][r], ui = eo[p + 2][r];
                    eo[p][r]     = ur * fr - ui * fi;
                    eo[p + 2][r] = ur * fi + ui * fr;
                }
            }
        }
        #pragma unroll
        for (int nt = 0; nt < 4; ++nt) {
            int n = nt * 16 + l15;
            #pragma unroll
            for (int r = 0; r < 4; ++r)
                O[(tok0 + rowb + r) * 64 + n] = eo[nt][r];
        }
    }
}

// ---------------- K5c: dec GEMM (f32 A, in-place safe), 2 tiles per block ---
__global__ __launch_bounds__(256) void k5c_dec(
        const float* A, const unsigned short* __restrict__ Bt, float* O) {
    __shared__ __align__(16) unsigned short fA[64 * 64];
    __shared__ __align__(16) unsigned short bst[64 * 64];
    int tid = threadIdx.x;
    int lane = tid & 63, wv = tid >> 6;
    int l15 = lane & 15, g = lane >> 4;
    int row0 = wv * 16 + l15;
    int rowb = wv * 16 + g * 4;
    #pragma unroll
    for (int i = 0; i < 2; ++i)
        *(short8v*)&bst[(i * 256 + tid) * 8] = *(const short8v*)&Bt[(i * 256 + tid) * 8];

    #pragma unroll
    for (int tile = 0; tile < 2; ++tile) {
        size_t tok0 = ((size_t)blockIdx.x * 2 + tile) * 64;
        if (tile) __syncthreads();
        #pragma unroll
        for (int r = 0; r < 16; ++r) {
            int idx = r * 256 + tid;
            int tok = idx >> 6, c = idx & 63;
            fA[tok * 64 + (c & 7) + 8 * ((c >> 3) ^ (tok & 7))] = f2b(A[(tok0 + tok) * 64 + c]);
        }
        __syncthreads();
        short8v a1[2];
        #pragma unroll
        for (int st = 0; st < 2; ++st)
            a1[st] = *(const short8v*)&fA[row0 * 64 + (((st * 4 + g) ^ (row0 & 7))) * 8];
        f32x4 eo[4];
        #pragma unroll
        for (int i = 0; i < 4; ++i) eo[i] = (f32x4)0.f;
        #pragma unroll
        for (int st = 0; st < 2; ++st) {
            #pragma unroll
            for (int nt = 0; nt < 4; ++nt) {
                int n = nt * 16 + l15;
                short8v b = *(const short8v*)&bst[n * 64 + (((st * 4 + g) ^ (n & 7))) * 8];
                eo[nt] = __builtin_amdgcn_mfma_f32_16x16x32_bf16(a1[st], b, eo[nt], 0, 0, 0);
            }
        }
        #pragma unroll
        for (int nt = 0; nt < 4; ++nt) {
            int n = nt * 16 + l15;
            #pragma unroll
            for (int r = 0; r < 4; ++r)
                O[(tok0 + rowb + r) * 64 + n] = eo[nt][r];
        }
    }
}

// ---------------- K5b: time scan + noise, pure streaming (in-place) ---------
__global__ __launch_bounds__(256) void k5b_scan(
        float* U, const float* __restrict__ tabs, const float* __restrict__ dt,
        const float* __restrict__ eps_re, const float* __restrict__ eps_im) {
    int gid = blockIdx.x * 256 + threadIdx.x;   // px*32 + d
    int px = gid >> 5, d = gid & 31;
    float Yr = 0.f, Yi = 0.f;
    for (int t = 0; t < TT; ++t) {
        size_t tok = (size_t)t * PX + px;
        float usr = U[tok * 64 + d], usi = U[tok * 64 + 32 + d];
        float dr = tabs[t * 32 + d], di = tabs[1024 + t * 32 + d];
        float nYr = dr * Yr - di * Yi + usr;
        float nYi = dr * Yi + di * Yr + usi;
        Yr = nYr; Yi = nYi;
        float s = 0.01f * sqrtf(dt[t]);
        size_t ei = tok * 32 + d;
        float epr = eps_re[ei], epi = eps_im[ei];
        U[tok * 64 + d]      = Yr + s * (Yr * epr - Yi * epi);
        U[tok * 64 + 32 + d] = Yi + s * (Yr * epi + Yi * epr);
    }
}

// ---------------- K6: LN2 + gated MoE MLP — R14-proven (96 µs) --------------
__global__ __launch_bounds__(256, 4) void k6_moe(
        const float* __restrict__ xo,
        const float* __restrict__ g2, const float* __restrict__ b2ln,
        const float* __restrict__ wg,
        const unsigned short* __restrict__ w1t, const float* __restrict__ b1,
        const unsigned short* __restrict__ w2t, const float* __restrict__ b2m,
        const float* __restrict__ xre, const float* __restrict__ xim,
        float* __restrict__ out) {
    __shared__ __align__(16) float hdl[64 * 65];           // H bf16[64][128] / delta f32[64][65]
    __shared__ __align__(16) unsigned short wst[8192];     // one weight matrix
    __shared__ float wgl[256];
    unsigned short* H = (unsigned short*)hdl;

    int tid = threadIdx.x;
    int lane = tid & 63;
    int wv = tid >> 6;
    int l15 = lane & 15, g = lane >> 4;
    int t = blockIdx.x >> 6;
    int px0 = (blockIdx.x & 63) * 64;
    int tok = wv * 16 + l15;
    int tsw = tok & 7;

    wgl[tid] = wg[tid];

    float f[16];
    {
        const float* src = xo + ((size_t)t * PX + px0 + tok) * 64 + g * 8;
        #pragma unroll
        for (int st = 0; st < 2; ++st) {
            float4 v0 = *(const float4*)&src[st * 32];
            float4 v1 = *(const float4*)&src[st * 32 + 4];
            f[st*8+0]=v0.x; f[st*8+1]=v0.y; f[st*8+2]=v0.z; f[st*8+3]=v0.w;
            f[st*8+4]=v1.x; f[st*8+5]=v1.y; f[st*8+6]=v1.z; f[st*8+7]=v1.w;
        }
    }
    float s = 0.f, ss = 0.f;
    #pragma unroll
    for (int i = 0; i < 16; ++i) { s += f[i]; ss += f[i] * f[i]; }
    s += __shfl_xor(s, 16); ss += __shfl_xor(ss, 16);
    s += __shfl_xor(s, 32); ss += __shfl_xor(ss, 32);
    float m = s * (1.f / 64.f);
    float rs = rsqrtf(ss * (1.f / 64.f) - m * m + 1e-5f);
    #pragma unroll
    for (int st = 0; st < 2; ++st) {
        int c0 = st * 32 + g * 8;
        float4 gv0 = *(const float4*)&g2[c0],   gv1 = *(const float4*)&g2[c0 + 4];
        float4 bv0 = *(const float4*)&b2ln[c0], bv1 = *(const float4*)&b2ln[c0 + 4];
        f[st*8+0] = (f[st*8+0]-m)*rs*gv0.x + bv0.x;
        f[st*8+1] = (f[st*8+1]-m)*rs*gv0.y + bv0.y;
        f[st*8+2] = (f[st*8+2]-m)*rs*gv0.z + bv0.z;
        f[st*8+3] = (f[st*8+3]-m)*rs*gv0.w + bv0.w;
        f[st*8+4] = (f[st*8+4]-m)*rs*gv1.x + bv1.x;
        f[st*8+5] = (f[st*8+5]-m)*rs*gv1.y + bv1.y;
        f[st*8+6] = (f[st*8+6]-m)*rs*gv1.z + bv1.z;
        f[st*8+7] = (f[st*8+7]-m)*rs*gv1.w + bv1.w;
    }
    __syncthreads();   // wgl visible
    float gt[4];
    {
        float g0 = 0.f, g1 = 0.f, g2_ = 0.f, g3 = 0.f;
        #pragma unroll
        for (int st = 0; st < 2; ++st)
            #pragma unroll
            for (int j = 0; j < 8; ++j) {
                int c = st * 32 + g * 8 + j;
                float fv = f[st * 8 + j];
                g0 += fv * wgl[c*4];   g1 += fv * wgl[c*4+1];
                g2_ += fv * wgl[c*4+2]; g3 += fv * wgl[c*4+3];
            }
        g0 += __shfl_xor(g0, 16); g1 += __shfl_xor(g1, 16);
        g2_ += __shfl_xor(g2_, 16); g3 += __shfl_xor(g3, 16);
        g0 += __shfl_xor(g0, 32); g1 += __shfl_xor(g1, 32);
        g2_ += __shfl_xor(g2_, 32); g3 += __shfl_xor(g3, 32);
        float mx = fmaxf(fmaxf(g0, g1), fmaxf(g2_, g3));
        float e0 = expf(g0-mx), e1 = expf(g1-mx), e2 = expf(g2_-mx), e3 = expf(g3-mx);
        float inv = 1.f / (e0 + e1 + e2 + e3);
        gt[0] = e0*inv; gt[1] = e1*inv; gt[2] = e2*inv; gt[3] = e3*inv;
    }
    short8v bf1[2];
    #pragma unroll
    for (int st = 0; st < 2; ++st)
        #pragma unroll
        for (int j = 0; j < 8; ++j)
            bf1[st][j] = (short)f2b(f[st * 8 + j]);

    f32x4 dacc[4];
    #pragma unroll
    for (int i = 0; i < 4; ++i) dacc[i] = (f32x4)0.f;

    for (int e = 0; e < 4; ++e) {
        __syncthreads();   // prev GEMM2 done reading wst/H
        {
            const short8v* gp = (const short8v*)(w1t + (size_t)e * 8192);
            #pragma unroll
            for (int i = 0; i < 4; ++i)
                *(short8v*)&wst[(i * 256 + tid) * 8] = gp[i * 256 + tid];
        }
        __syncthreads();   // w1e ready
        f32x4 h[8];
        #pragma unroll
        for (int i = 0; i < 8; ++i) h[i] = (f32x4)0.f;
        #pragma unroll
        for (int st = 0; st < 2; ++st) {
            #pragma unroll
            for (int ft = 0; ft < 8; ++ft) {
                int fi = ft * 16 + l15;
                short8v a = *(const short8v*)&wst[fi * 64 + (((st * 4 + g) ^ (fi & 7))) * 8];
                h[ft] = __builtin_amdgcn_mfma_f32_16x16x32_bf16(a, bf1[st], h[ft], 0, 0, 0);
            }
        }
        #pragma unroll
        for (int ft = 0; ft < 8; ++ft) {
            int f0 = ft * 16 + g * 4;
            float4 bb = *(const float4*)&b1[e * 128 + f0];
            unsigned short p0 = f2b(gelu_fast(h[ft][0] + bb.x));
            unsigned short p1 = f2b(gelu_fast(h[ft][1] + bb.y));
            unsigned short p2 = f2b(gelu_fast(h[ft][2] + bb.z));
            unsigned short p3 = f2b(gelu_fast(h[ft][3] + bb.w));
            unsigned long long pk = (unsigned long long)p0 | ((unsigned long long)p1 << 16)
                                  | ((unsigned long long)p2 << 32) | ((unsigned long long)p3 << 48);
            *(unsigned long long*)&H[tok * 128 + (f0 & 7) + 8 * ((f0 >> 3) ^ tsw)] = pk;
        }
        __syncthreads();   // GEMM1 wst reads done + H complete
        {
            const short8v* gp = (const short8v*)(w2t + (size_t)e * 8192);
            #pragma unroll
            for (int i = 0; i < 4; ++i)
                *(short8v*)&wst[(i * 256 + tid) * 8] = gp[i * 256 + tid];
        }
        __syncthreads();   // w2e ready
        f32x4 eo[4];
        #pragma unroll
        for (int i = 0; i < 4; ++i) eo[i] = (f32x4)0.f;
        #pragma unroll
        for (int st = 0; st < 4; ++st) {
            short8v bh = *(const short8v*)&H[tok * 128 + (((st * 4 + g) ^ tsw)) * 8];
            #pragma unroll
            for (int nt = 0; nt < 4; ++nt) {
                int n = nt * 16 + l15;
                short8v a = *(const short8v*)&wst[n * 128 + (((st * 4 + g) ^ (n & 7))) * 8];
                eo[nt] = __builtin_amdgcn_mfma_f32_16x16x32_bf16(a, bh, eo[nt], 0, 0, 0);
            }
        }
        float ge = gt[e];
        #pragma unroll
        for (int nt = 0; nt < 4; ++nt) {
            int n0 = nt * 16 + g * 4;
            float4 bb = *(const float4*)&b2m[e * 64 + n0];
            dacc[nt][0] += ge * (eo[nt][0] + bb.x);
            dacc[nt][1] += ge * (eo[nt][1] + bb.y);
            dacc[nt][2] += ge * (eo[nt][2] + bb.z);
            dacc[nt][3] += ge * (eo[nt][3] + bb.w);
        }
    }
    __syncthreads();   // all H reads done; reuse hdl as f32 delta [64][65]
    float* dl = hdl;
    #pragma unroll
    for (int nt = 0; nt < 4; ++nt) {
        int n0 = nt * 16 + g * 4;
        #pragma unroll
        for (int r = 0; r < 4; ++r)
            dl[tok * 65 + n0 + r] = dacc[nt][r];
    }
    __syncthreads();
    #pragma unroll
    for (int st = 0; st < 2; ++st) {
        const float* xsrc = (st == 0) ? xre : xim;
        float* osrc = out + (st == 0 ? 0 : (size_t)4194304);
        #pragma unroll
        for (int j = 0; j < 8; ++j) {
            int c = st * 32 + g * 8 + j;
            float val = b2f((unsigned short)bf1[st][j]) + dl[tok * 65 + c];
            size_t xi_ = ((size_t)t * 32 + (c & 31)) * PX + px0 + tok;
            osrc[xi_] = val + xsrc[xi_];
        }
    }
}

extern "C" void kernel_launch(void* const* d_in, const int* in_sizes, int n_in,
                              void* d_out, int out_size, void* d_ws, size_t ws_size,
                              hipStream_t stream) {
    const float* xre   = (const float*)d_in[0];
    const float* xim   = (const float*)d_in[1];
    const float* dt    = (const float*)d_in[2];
    const float* epsre = (const float*)d_in[3];
    const float* epsim = (const float*)d_in[4];
    const float* ln1g  = (const float*)d_in[5];
    const float* ln1b  = (const float*)d_in[6];
    const float* ln2g  = (const float*)d_in[7];
    const float* ln2b  = (const float*)d_in[8];
    const float* convw = (const float*)d_in[9];
    const float* convb = (const float*)d_in[10];
    const float* encre = (const float*)d_in[11];
    const float* encim = (const float*)d_in[12];
    const float* decre = (const float*)d_in[13];
    const float* decim = (const float*)d_in[14];
    const float* lamre = (const float*)d_in[15];
    const float* lamim = (const float*)d_in[16];
    const float* alpha = (const float*)d_in[17];
    const float* fwre  = (const float*)d_in[18];
    const float* fwim  = (const float*)d_in[19];
    const float* wg    = (const float*)d_in[20];
    const float* w1    = (const float*)d_in[21];
    const float* b1    = (const float*)d_in[22];
    const float* w2    = (const float*)d_in[23];
    const float* b2    = (const float*)d_in[24];
    float* out = (float*)d_out;

    float* ws = (float*)d_ws;
    // region A [0, 8.4M floats): xpad bf16 (17.8MB, dead after k2)
    //   -> U f32 (33.5MB, k5a output) -> xo f32 (k5c in-place) -> k6 input
    unsigned short* xpad = (unsigned short*)ws;
    float* U    = ws;
    float* xo   = ws;
    // region B [8.4M, 16.8M floats): xs bf16 (16.8MB)
    unsigned short* xsb = (unsigned short*)(ws + 8388608);
    float* mean = ws + 16777216;
    float* tabs = ws + 16779264;
    unsigned short* w1t = (unsigned short*)(ws + 16783360);
    unsigned short* w2t = w1t + 32768;
    unsigned short* w9t = w2t + 32768;
    unsigned short* benct = w9t + 36864;
    unsigned short* bdect = benct + 4096;

    k0_prep<<<432, 256, 0, stream>>>(w1, w2, convw, encre, encim, decre, decim,
                                     w1t, w2t, w9t, benct, bdect);
    kz_halo<<<33, 256, 0, stream>>>(xpad);
    k1_ln1<<<512, 256, 0, stream>>>(xre, xim, ln1g, ln1b, xpad);
    k2_conv<<<512, 256, 0, stream>>>(xpad, w9t, convb, xsb);
    k3_mean<<<32, 256, 0, stream>>>(xsb, mean);
    k4_ops<<<1, 256, 0, stream>>>(dt, lamre, lamim, alpha, fwre, fwim, mean,
                                  tabs, out + 8388608);
    k5a_enc<<<1024, 256, 0, stream>>>(xsb, benct, tabs, U);       // u*forcing
    k5b_scan<<<512, 256, 0, stream>>>(U, tabs, dt, epsre, epsim); // scan+noise
    k5c_dec<<<1024, 256, 0, stream>>>(U, bdect, xo);              // dec (in-place)
    k6_moe<<<2048, 256, 0, stream>>>(xo, ln2g, ln2b, wg, w1t, b1, w2t, b2,
                                     xre, xim, out);
}

// Round 18
// 255.730 us; speedup vs baseline: 1.0602x; 1.0602x over previous
//
#include <hip/hip_runtime.h>
#include <math.h>

#define PX 4096   // 64*64
#define TT 32
#define DD 32
#define CC 64     // 2*D
#define PW 66     // padded width
#define PPX 4356  // 66*66

typedef __attribute__((ext_vector_type(8))) short short8v;
typedef __attribute__((ext_vector_type(4))) float f32x4;

__device__ __forceinline__ float gelu_fast(float x) {
    float u = x * x;
    float a = x * (1.5957691216057308f + 0.07135481627f * u);
    return x / (1.0f + __expf(-a));
}

__device__ __forceinline__ unsigned short f2b(float x) {
    union { float f; unsigned u; } v; v.f = x;
    unsigned r = v.u + 0x7FFF + ((v.u >> 16) & 1);
    return (unsigned short)(r >> 16);
}

__device__ __forceinline__ float b2f(unsigned short b) {
    union { unsigned u; float f; } v; v.u = ((unsigned)b) << 16;
    return v.f;
}

// ---------------- K1: LN1 (64ch) fused -> padded bf16 NHWC ------------------
__global__ __launch_bounds__(256) void k1_ln1(
        const float* __restrict__ xre, const float* __restrict__ xim,
        const float* __restrict__ g, const float* __restrict__ b,
        unsigned short* __restrict__ xpad) {
    int gid = blockIdx.x * 256 + threadIdx.x;   // t*4096 + px
    int t = gid >> 12, px = gid & 4095;
    int row = px >> 6, col = px & 63;
    const float* pr = xre + (size_t)t * DD * PX + px;
    const float* pi = xim + (size_t)t * DD * PX + px;
    float s = 0.f, ss = 0.f;
    #pragma unroll
    for (int d = 0; d < DD; ++d) {
        float vr = pr[d * PX], vi = pi[d * PX];
        s += vr + vi; ss += vr * vr + vi * vi;
    }
    float m = s * (1.f / 64.f);
    float var = ss * (1.f / 64.f) - m * m;
    float rs = rsqrtf(var + 1e-5f);
    unsigned short* o = xpad + ((size_t)t * PPX + (row + 1) * PW + (col + 1)) * 64;
    #pragma unroll
    for (int j = 0; j < 8; ++j) {
        short8v v8;
        #pragma unroll
        for (int dd = 0; dd < 8; ++dd) {
            int ch = j * 8 + dd;
            float v = (ch < 32) ? (pr[ch * PX] - m) * rs * g[ch] + b[ch]
                                : (pi[(ch - 32) * PX] - m) * rs * g[ch] + b[ch];
            v8[dd] = (short)f2b(v);
        }
        *(short8v*)&o[j * 8] = v8;
    }
}

// ---------------- K0: prep — weights bf16/transpose/swizzle + xpad halo -----
__global__ __launch_bounds__(256) void k0_prep(
        const float* __restrict__ w1, const float* __restrict__ w2,
        const float* __restrict__ convw,
        const float* __restrict__ encre, const float* __restrict__ encim,
        const float* __restrict__ decre, const float* __restrict__ decim,
        unsigned short* __restrict__ w1t, unsigned short* __restrict__ w2t,
        unsigned short* __restrict__ w9t,
        unsigned short* __restrict__ benct, unsigned short* __restrict__ bdect,
        unsigned short* __restrict__ xpad) {
    int gid = blockIdx.x * 256 + threadIdx.x;
    if (gid < 32768) {
        int idx = gid;
        int e = idx >> 13, r = idx & 8191;
        int f = r >> 6, p = r & 63;
        int c = (p & 7) + 8 * ((p >> 3) ^ (f & 7));
        w1t[idx] = f2b(w1[((size_t)e * 64 + c) * 128 + f]);
    } else if (gid < 65536) {
        int idx = gid - 32768;
        int e = idx >> 13, r = idx & 8191;
        int n = r >> 7, p = r & 127;
        int f = (p & 7) + 8 * ((p >> 3) ^ (n & 7));
        w2t[idx] = f2b(w2[((size_t)e * 128 + f) * 64 + n]);
    } else if (gid < 102400) {
        int idx = gid - 65536;
        int tap = idx >> 12, rem = idx & 4095;
        int n = rem >> 6, p = rem & 63;
        int k = (p & 7) + 8 * ((p >> 3) ^ (n & 7));
        w9t[idx] = f2b(convw[((size_t)n * 64 + k) * 9 + tap]);
    } else if (gid < 110592) {
        int idx = gid - 102400;
        const float* Rr = (idx < 4096) ? encre : decre;
        const float* Ri = (idx < 4096) ? encim : decim;
        unsigned short* dst = (idx < 4096) ? benct : bdect;
        idx &= 4095;
        int n = idx >> 6, p = idx & 63;
        int k = (p & 7) + 8 * ((p >> 3) ^ (n & 7));
        float v;
        if (n < 32) v = (k < 32) ? Rr[k * 32 + n] : -Ri[(k - 32) * 32 + n];
        else        v = (k < 32) ? Ri[k * 32 + (n - 32)] : Rr[(k - 32) * 32 + (n - 32)];
        dst[idx] = f2b(v);
    } else if (gid < 110592 + 32 * 260) {
        int idx = gid - 110592;                 // halo zeroing (was kz_halo)
        int im = idx / 260, h = idx % 260;
        int row, col;
        if (h < 66)       { row = 0;  col = h; }
        else if (h < 132) { row = 65; col = h - 66; }
        else { int hh = h - 132; row = 1 + (hh >> 1); col = (hh & 1) * 65; }
        unsigned short* p = xpad + ((size_t)im * PPX + row * PW + col) * 64;
        short8v z = (short8v)0;
        #pragma unroll
        for (int j = 0; j < 8; ++j) *(short8v*)&p[j * 8] = z;
    }
}

// ---------------- K2: 3x3 conv 64->64 as 9-tap implicit GEMM (bf16 MFMA) ----
__global__ __launch_bounds__(256, 2) void k2_conv(
        const unsigned short* __restrict__ xpad,
        const unsigned short* __restrict__ w9t,
        const float* __restrict__ bias, float* __restrict__ xs) {
    __shared__ __align__(16) unsigned short wst[36864];   // 9 taps x 64oc x 64ic swz
    int tid = threadIdx.x;
    int bid = blockIdx.x;
    int lb = (bid & 7) * 64 + (bid >> 3);   // bijective (512 % 8 == 0)
    int t = lb >> 4, rg = lb & 15;
    int lane = tid & 63, wv = tid >> 6;
    int l15 = lane & 15, g = lane >> 4;
    #pragma unroll
    for (int i = 0; i < 18; ++i) {
        int idx = i * 256 + tid;
        *(short8v*)&wst[idx * 8] = *(const short8v*)&w9t[idx * 8];
    }
    __syncthreads();
    int r = rg * 4 + wv;
    const unsigned short* xb = xpad + (size_t)t * PPX * 64;
    f32x4 acc[4][4];
    #pragma unroll
    for (int m = 0; m < 4; ++m)
        #pragma unroll
        for (int nt = 0; nt < 4; ++nt) acc[m][nt] = (f32x4)0.f;

    #pragma unroll
    for (int kh = 0; kh < 3; ++kh) {
        #pragma unroll
        for (int kw = 0; kw < 3; ++kw) {
            int tap = kh * 3 + kw;
            #pragma unroll
            for (int kc = 0; kc < 2; ++kc) {
                short8v a[4];
                #pragma unroll
                for (int m = 0; m < 4; ++m) {
                    int pcol = m * 16 + l15 + kw;
                    a[m] = *(const short8v*)&xb[((size_t)(r + kh) * PW + pcol) * 64 + kc * 32 + g * 8];
                }
                #pragma unroll
                for (int nt = 0; nt < 4; ++nt) {
                    int n = nt * 16 + l15;
                    short8v bf = *(const short8v*)&wst[tap * 4096 + n * 64 + ((kc * 4 + g) ^ (n & 7)) * 8];
                    #pragma unroll
                    for (int m = 0; m < 4; ++m)
                        acc[m][nt] = __builtin_amdgcn_mfma_f32_16x16x32_bf16(a[m], bf, acc[m][nt], 0, 0, 0);
                }
            }
        }
    }
    float* dst = xs + ((size_t)t * PX + r * 64) * 64;
    #pragma unroll
    for (int nt = 0; nt < 4; ++nt) {
        float bo = bias[nt * 16 + l15];
        #pragma unroll
        for (int m = 0; m < 4; ++m) {
            #pragma unroll
            for (int reg = 0; reg < 4; ++reg) {
                int tok = m * 16 + g * 4 + reg;
                dst[(size_t)tok * 64 + nt * 16 + l15] = acc[m][nt][reg] + bo;
            }
        }
    }
}

// ---------------- K3: per-(t,c) spatial mean (NHWC input) -------------------
__global__ __launch_bounds__(256) void k3_mean(
        const float* __restrict__ xs, float* __restrict__ mean) {
    __shared__ f32x4 red[256];
    int t = blockIdx.x;
    int c4 = threadIdx.x & 15, q = threadIdx.x >> 4;
    const float* base = xs + (size_t)t * PX * 64 + c4 * 4;
    f32x4 s = (f32x4)0.f;
    for (int px = q; px < PX; px += 16)
        s += *(const f32x4*)&base[(size_t)px * 64];
    red[threadIdx.x] = s;
    __syncthreads();
    for (int st = 8; st > 0; st >>= 1) {
        if (q < st) red[q * 16 + c4] += red[(q + st) * 16 + c4];
        __syncthreads();
    }
    if (q == 0) {
        f32x4 v = red[c4] * (1.f / 4096.f);
        *(f32x4*)&mean[t * 64 + c4 * 4] = v;
    }
}

// ---------------- K4: decay/forcing tables + flux scan ----------------------
__global__ __launch_bounds__(256) void k4_ops(
        const float* __restrict__ dt, const float* __restrict__ lam_re,
        const float* __restrict__ lam_im, const float* __restrict__ alpha,
        const float* __restrict__ wre, const float* __restrict__ wim,
        const float* __restrict__ mean, float* __restrict__ tabs,
        float* __restrict__ outflux) {
    int tid = threadIdx.x;
    for (int idx = tid; idx < 1024; idx += 256) {
        int t = idx >> 5, d = idx & 31;
        float x = lam_re[d];
        float sp = (x > 0.f) ? x + log1pf(expf(-x)) : log1pf(expf(x));
        float lr = -sp, li = lam_im[d];
        float dtv = dt[t];
        float er = expf(lr * dtv);
        float dr = er * cosf(li * dtv);
        float di = er * sinf(li * dtv);
        float den = lr * lr + li * li;
        float fr = ((dr - 1.f) * lr + di * li) / den;
        float fi = (di * lr - (dr - 1.f) * li) / den;
        tabs[idx] = dr; tabs[1024 + idx] = di;
        tabs[2048 + idx] = fr; tabs[3072 + idx] = fi;
    }
    if (tid < 32) {
        int d = tid;
        float a = 1.f / (1.f + expf(-alpha[d]));
        float yr = 0.f, yi = 0.f;
        for (int t = 0; t < 32; ++t) {
            float xr = 0.f, xi = 0.f;
            for (int k = 0; k < 32; ++k) {
                float mr = mean[t * 64 + k], mi = mean[t * 64 + 32 + k];
                float wr = wre[k * 32 + d], wi = wim[k * 32 + d];
                xr += mr * wr - mi * wi;
                xi += mr * wi + mi * wr;
            }
            yr = a * yr + xr; yi = a * yi + xi;
        }
        outflux[d] = yr; outflux[32 + d] = yi;
    }
}

// ---------------- K5a/K5c: token GEMM, 2 tiles (128 tok) per block ----------
template<bool FORCING>
__global__ __launch_bounds__(256) void k5_gemm(
        const float* A, const unsigned short* __restrict__ Bt,
        const float* __restrict__ tabs, float* O) {
    __shared__ __align__(16) unsigned short fA[64 * 64];
    __shared__ __align__(16) unsigned short bst[64 * 64];
    int tid = threadIdx.x;
    int lane = tid & 63, wv = tid >> 6;
    int l15 = lane & 15, g = lane >> 4;
    int row0 = wv * 16 + l15;
    int rowb = wv * 16 + g * 4;
    #pragma unroll
    for (int i = 0; i < 2; ++i)
        *(short8v*)&bst[(i * 256 + tid) * 8] = *(const short8v*)&Bt[(i * 256 + tid) * 8];

    #pragma unroll
    for (int tile = 0; tile < 2; ++tile) {
        size_t tok0 = ((size_t)blockIdx.x * 2 + tile) * 64;
        if (tile) __syncthreads();   // prev tile's fA fragment reads done
        #pragma unroll
        for (int r = 0; r < 16; ++r) {
            int idx = r * 256 + tid;
            int tok = idx >> 6, c = idx & 63;
            fA[tok * 64 + (c & 7) + 8 * ((c >> 3) ^ (tok & 7))] = f2b(A[(tok0 + tok) * 64 + c]);
        }
        __syncthreads();   // fA (+bst on tile 0) ready
        short8v a1[2];
        #pragma unroll
        for (int st = 0; st < 2; ++st)
            a1[st] = *(const short8v*)&fA[row0 * 64 + (((st * 4 + g) ^ (row0 & 7))) * 8];
        f32x4 eo[4];
        #pragma unroll
        for (int i = 0; i < 4; ++i) eo[i] = (f32x4)0.f;
        #pragma unroll
        for (int st = 0; st < 2; ++st) {
            #pragma unroll
            for (int nt = 0; nt < 4; ++nt) {
                int n = nt * 16 + l15;
                short8v b = *(const short8v*)&bst[n * 64 + (((st * 4 + g) ^ (n & 7))) * 8];
                eo[nt] = __builtin_amdgcn_mfma_f32_16x16x32_bf16(a1[st], b, eo[nt], 0, 0, 0);
            }
        }
        if (FORCING) {
            int t = (int)(tok0 >> 12);
            #pragma unroll
            for (int p = 0; p < 2; ++p) {
                int d = p * 16 + l15;
                float fr = tabs[2048 + t * 32 + d], fi = tabs[3072 + t * 32 + d];
                #pragma unroll
                for (int r = 0; r < 4; ++r) {
                    float ur = eo[p][r], ui = eo[p + 2][r];
                    eo[p][r]     = ur * fr - ui * fi;
                    eo[p + 2][r] = ur * fi + ui * fr;
                }
            }
        }
        #pragma unroll
        for (int nt = 0; nt < 4; ++nt) {
            int n = nt * 16 + l15;
            #pragma unroll
            for (int r = 0; r < 4; ++r)
                O[(tok0 + rowb + r) * 64 + n] = eo[nt][r];
        }
    }
}

// ---------------- K5b: time scan + noise, pure streaming (in-place) ---------
__global__ __launch_bounds__(256) void k5b_scan(
        float* U, const float* __restrict__ tabs, const float* __restrict__ dt,
        const float* __restrict__ eps_re, const float* __restrict__ eps_im) {
    int gid = blockIdx.x * 256 + threadIdx.x;   // px*32 + d
    int px = gid >> 5, d = gid & 31;
    float Yr = 0.f, Yi = 0.f;
    for (int t = 0; t < TT; ++t) {
        size_t tok = (size_t)t * PX + px;
        float usr = U[tok * 64 + d], usi = U[tok * 64 + 32 + d];
        float dr = tabs[t * 32 + d], di = tabs[1024 + t * 32 + d];
        float nYr = dr * Yr - di * Yi + usr;
        float nYi = dr * Yi + di * Yr + usi;
        Yr = nYr; Yi = nYi;
        float s = 0.01f * sqrtf(dt[t]);
        size_t ei = tok * 32 + d;
        float epr = eps_re[ei], epi = eps_im[ei];
        U[tok * 64 + d]      = Yr + s * (Yr * epr - Yi * epi);
        U[tok * 64 + 32 + d] = Yi + s * (Yr * epi + Yi * epr);
    }
}

// ---------------- K6: LN2 + gated MoE MLP — R9/R14-proven (96 µs) -----------
__global__ __launch_bounds__(256, 4) void k6_moe(
        const float* __restrict__ xo,
        const float* __restrict__ g2, const float* __restrict__ b2ln,
        const float* __restrict__ wg,
        const unsigned short* __restrict__ w1t, const float* __restrict__ b1,
        const unsigned short* __restrict__ w2t, const float* __restrict__ b2m,
        const float* __restrict__ xre, const float* __restrict__ xim,
        float* __restrict__ out) {
    __shared__ __align__(16) float hdl[64 * 65];           // H bf16[64][128] / delta f32[64][65]
    __shared__ __align__(16) unsigned short wst[8192];     // one weight matrix
    __shared__ float wgl[256];
    unsigned short* H = (unsigned short*)hdl;

    int tid = threadIdx.x;
    int lane = tid & 63;
    int wv = tid >> 6;
    int l15 = lane & 15, g = lane >> 4;
    int t = blockIdx.x >> 6;
    int px0 = (blockIdx.x & 63) * 64;
    int tok = wv * 16 + l15;
    int tsw = tok & 7;

    wgl[tid] = wg[tid];

    float f[16];
    {
        const float* src = xo + ((size_t)t * PX + px0 + tok) * 64 + g * 8;
        #pragma unroll
        for (int st = 0; st < 2; ++st) {
            float4 v0 = *(const float4*)&src[st * 32];
            float4 v1 = *(const float4*)&src[st * 32 + 4];
            f[st*8+0]=v0.x; f[st*8+1]=v0.y; f[st*8+2]=v0.z; f[st*8+3]=v0.w;
            f[st*8+4]=v1.x; f[st*8+5]=v1.y; f[st*8+6]=v1.z; f[st*8+7]=v1.w;
        }
    }
    float s = 0.f, ss = 0.f;
    #pragma unroll
    for (int i = 0; i < 16; ++i) { s += f[i]; ss += f[i] * f[i]; }
    s += __shfl_xor(s, 16); ss += __shfl_xor(ss, 16);
    s += __shfl_xor(s, 32); ss += __shfl_xor(ss, 32);
    float m = s * (1.f / 64.f);
    float rs = rsqrtf(ss * (1.f / 64.f) - m * m + 1e-5f);
    #pragma unroll
    for (int st = 0; st < 2; ++st) {
        int c0 = st * 32 + g * 8;
        float4 gv0 = *(const float4*)&g2[c0],   gv1 = *(const float4*)&g2[c0 + 4];
        float4 bv0 = *(const float4*)&b2ln[c0], bv1 = *(const float4*)&b2ln[c0 + 4];
        f[st*8+0] = (f[st*8+0]-m)*rs*gv0.x + bv0.x;
        f[st*8+1] = (f[st*8+1]-m)*rs*gv0.y + bv0.y;
        f[st*8+2] = (f[st*8+2]-m)*rs*gv0.z + bv0.z;
        f[st*8+3] = (f[st*8+3]-m)*rs*gv0.w + bv0.w;
        f[st*8+4] = (f[st*8+4]-m)*rs*gv1.x + bv1.x;
        f[st*8+5] = (f[st*8+5]-m)*rs*gv1.y + bv1.y;
        f[st*8+6] = (f[st*8+6]-m)*rs*gv1.z + bv1.z;
        f[st*8+7] = (f[st*8+7]-m)*rs*gv1.w + bv1.w;
    }
    __syncthreads();   // wgl visible
    float gt[4];
    {
        float g0 = 0.f, g1 = 0.f, g2_ = 0.f, g3 = 0.f;
        #pragma unroll
        for (int st = 0; st < 2; ++st)
            #pragma unroll
            for (int j = 0; j < 8; ++j) {
                int c = st * 32 + g * 8 + j;
                float fv = f[st * 8 + j];
                g0 += fv * wgl[c*4];   g1 += fv * wgl[c*4+1];
                g2_ += fv * wgl[c*4+2]; g3 += fv * wgl[c*4+3];
            }
        g0 += __shfl_xor(g0, 16); g1 += __shfl_xor(g1, 16);
        g2_ += __shfl_xor(g2_, 16); g3 += __shfl_xor(g3, 16);
        g0 += __shfl_xor(g0, 32); g1 += __shfl_xor(g1, 32);
        g2_ += __shfl_xor(g2_, 32); g3 += __shfl_xor(g3, 32);
        float mx = fmaxf(fmaxf(g0, g1), fmaxf(g2_, g3));
        float e0 = expf(g0-mx), e1 = expf(g1-mx), e2 = expf(g2_-mx), e3 = expf(g3-mx);
        float inv = 1.f / (e0 + e1 + e2 + e3);
        gt[0] = e0*inv; gt[1] = e1*inv; gt[2] = e2*inv; gt[3] = e3*inv;
    }
    short8v bf1[2];
    #pragma unroll
    for (int st = 0; st < 2; ++st)
        #pragma unroll
        for (int j = 0; j < 8; ++j)
            bf1[st][j] = (short)f2b(f[st * 8 + j]);

    f32x4 dacc[4];
    #pragma unroll
    for (int i = 0; i < 4; ++i) dacc[i] = (f32x4)0.f;

    for (int e = 0; e < 4; ++e) {
        __syncthreads();   // prev GEMM2 done reading wst/H
        {
            const short8v* gp = (const short8v*)(w1t + (size_t)e * 8192);
            #pragma unroll
            for (int i = 0; i < 4; ++i)
                *(short8v*)&wst[(i * 256 + tid) * 8] = gp[i * 256 + tid];
        }
        __syncthreads();   // w1e ready
        f32x4 h[8];
        #pragma unroll
        for (int i = 0; i < 8; ++i) h[i] = (f32x4)0.f;
        #pragma unroll
        for (int st = 0; st < 2; ++st) {
            #pragma unroll
            for (int ft = 0; ft < 8; ++ft) {
                int fi = ft * 16 + l15;
                short8v a = *(const short8v*)&wst[fi * 64 + (((st * 4 + g) ^ (fi & 7))) * 8];
                h[ft] = __builtin_amdgcn_mfma_f32_16x16x32_bf16(a, bf1[st], h[ft], 0, 0, 0);
            }
        }
        #pragma unroll
        for (int ft = 0; ft < 8; ++ft) {
            int f0 = ft * 16 + g * 4;
            float4 bb = *(const float4*)&b1[e * 128 + f0];
            unsigned short p0 = f2b(gelu_fast(h[ft][0] + bb.x));
            unsigned short p1 = f2b(gelu_fast(h[ft][1] + bb.y));
            unsigned short p2 = f2b(gelu_fast(h[ft][2] + bb.z));
            unsigned short p3 = f2b(gelu_fast(h[ft][3] + bb.w));
            unsigned long long pk = (unsigned long long)p0 | ((unsigned long long)p1 << 16)
                                  | ((unsigned long long)p2 << 32) | ((unsigned long long)p3 << 48);
            *(unsigned long long*)&H[tok * 128 + (f0 & 7) + 8 * ((f0 >> 3) ^ tsw)] = pk;
        }
        __syncthreads();   // GEMM1 wst reads done + H complete
        {
            const short8v* gp = (const short8v*)(w2t + (size_t)e * 8192);
            #pragma unroll
            for (int i = 0; i < 4; ++i)
                *(short8v*)&wst[(i * 256 + tid) * 8] = gp[i * 256 + tid];
        }
        __syncthreads();   // w2e ready
        f32x4 eo[4];
        #pragma unroll
        for (int i = 0; i < 4; ++i) eo[i] = (f32x4)0.f;
        #pragma unroll
        for (int st = 0; st < 4; ++st) {
            short8v bh = *(const short8v*)&H[tok * 128 + (((st * 4 + g) ^ tsw)) * 8];
            #pragma unroll
            for (int nt = 0; nt < 4; ++nt) {
                int n = nt * 16 + l15;
                short8v a = *(const short8v*)&wst[n * 128 + (((st * 4 + g) ^ (n & 7))) * 8];
                eo[nt] = __builtin_amdgcn_mfma_f32_16x16x32_bf16(a, bh, eo[nt], 0, 0, 0);
            }
        }
        float ge = gt[e];
        #pragma unroll
        for (int nt = 0; nt < 4; ++nt) {
            int n0 = nt * 16 + g * 4;
            float4 bb = *(const float4*)&b2m[e * 64 + n0];
            dacc[nt][0] += ge * (eo[nt][0] + bb.x);
            dacc[nt][1] += ge * (eo[nt][1] + bb.y);
            dacc[nt][2] += ge * (eo[nt][2] + bb.z);
            dacc[nt][3] += ge * (eo[nt][3] + bb.w);
        }
    }
    __syncthreads();   // all H reads done; reuse hdl as f32 delta [64][65]
    float* dl = hdl;
    #pragma unroll
    for (int nt = 0; nt < 4; ++nt) {
        int n0 = nt * 16 + g * 4;
        #pragma unroll
        for (int r = 0; r < 4; ++r)
            dl[tok * 65 + n0 + r] = dacc[nt][r];
    }
    __syncthreads();
    #pragma unroll
    for (int st = 0; st < 2; ++st) {
        const float* xsrc = (st == 0) ? xre : xim;
        float* osrc = out + (st == 0 ? 0 : (size_t)4194304);
        #pragma unroll
        for (int j = 0; j < 8; ++j) {
            int c = st * 32 + g * 8 + j;
            float val = b2f((unsigned short)bf1[st][j]) + dl[tok * 65 + c];
            size_t xi_ = ((size_t)t * 32 + (c & 31)) * PX + px0 + tok;
            osrc[xi_] = val + xsrc[xi_];
        }
    }
}

extern "C" void kernel_launch(void* const* d_in, const int* in_sizes, int n_in,
                              void* d_out, int out_size, void* d_ws, size_t ws_size,
                              hipStream_t stream) {
    const float* xre   = (const float*)d_in[0];
    const float* xim   = (const float*)d_in[1];
    const float* dt    = (const float*)d_in[2];
    const float* epsre = (const float*)d_in[3];
    const float* epsim = (const float*)d_in[4];
    const float* ln1g  = (const float*)d_in[5];
    const float* ln1b  = (const float*)d_in[6];
    const float* ln2g  = (const float*)d_in[7];
    const float* ln2b  = (const float*)d_in[8];
    const float* convw = (const float*)d_in[9];
    const float* convb = (const float*)d_in[10];
    const float* encre = (const float*)d_in[11];
    const float* encim = (const float*)d_in[12];
    const float* decre = (const float*)d_in[13];
    const float* decim = (const float*)d_in[14];
    const float* lamre = (const float*)d_in[15];
    const float* lamim = (const float*)d_in[16];
    const float* alpha = (const float*)d_in[17];
    const float* fwre  = (const float*)d_in[18];
    const float* fwim  = (const float*)d_in[19];
    const float* wg    = (const float*)d_in[20];
    const float* w1    = (const float*)d_in[21];
    const float* b1    = (const float*)d_in[22];
    const float* w2    = (const float*)d_in[23];
    const float* b2    = (const float*)d_in[24];
    float* out = (float*)d_out;

    float* ws = (float*)d_ws;
    unsigned short* xpad = (unsigned short*)ws;   // region A: xpad bf16 then xo f32
    float* xo   = ws;
    float* xs   = ws + 8388608;         // NHWC f32: conv out -> U (in-place) -> W
    float* mean = ws + 16777216;
    float* tabs = ws + 16779264;
    unsigned short* w1t = (unsigned short*)(ws + 16783360);
    unsigned short* w2t = w1t + 32768;
    unsigned short* w9t = w2t + 32768;
    unsigned short* benct = w9t + 36864;
    unsigned short* bdect = benct + 4096;

    k0_prep<<<465, 256, 0, stream>>>(w1, w2, convw, encre, encim, decre, decim,
                                     w1t, w2t, w9t, benct, bdect, xpad);
    k1_ln1<<<512, 256, 0, stream>>>(xre, xim, ln1g, ln1b, xpad);
    k2_conv<<<512, 256, 0, stream>>>(xpad, w9t, convb, xs);
    k3_mean<<<32, 256, 0, stream>>>(xs, mean);
    k4_ops<<<1, 256, 0, stream>>>(dt, lamre, lamim, alpha, fwre, fwim, mean,
                                  tabs, out + 8388608);
    k5_gemm<true><<<1024, 256, 0, stream>>>(xs, benct, tabs, xs);   // u*forcing
    k5b_scan<<<512, 256, 0, stream>>>(xs, tabs, dt, epsre, epsim);  // scan+noise
    k5_gemm<false><<<1024, 256, 0, stream>>>(xs, bdect, tabs, xo);  // dec
    k6_moe<<<2048, 256, 0, stream>>>(xo, ln2g, ln2b, wg, w1t, b1, w2t, b2,
                                     xre, xim, out);
}

// Round 19
// 197.468 us; speedup vs baseline: 1.3729x; 1.2950x over previous
//
#include <hip/hip_runtime.h>
#include <math.h>

#define PX 4096   // 64*64
#define TT 32
#define DD 32
#define CC 64     // 2*D
#define PW 66     // padded width
#define PPX 4356  // 66*66

typedef __attribute__((ext_vector_type(8))) short short8v;
typedef __attribute__((ext_vector_type(4))) float f32x4;

__device__ __forceinline__ float gelu_fast(float x) {
    float u = x * x;
    float a = x * (1.5957691216057308f + 0.07135481627f * u);
    return x / (1.0f + __expf(-a));
}

__device__ __forceinline__ unsigned short f2b(float x) {
    union { float f; unsigned u; } v; v.f = x;
    unsigned r = v.u + 0x7FFF + ((v.u >> 16) & 1);
    return (unsigned short)(r >> 16);
}

__device__ __forceinline__ float b2f(unsigned short b) {
    union { unsigned u; float f; } v; v.u = ((unsigned)b) << 16;
    return v.f;
}

// ---------------- K1: LN1 (64ch) fused -> padded bf16 NHWC ------------------
__global__ __launch_bounds__(256) void k1_ln1(
        const float* __restrict__ xre, const float* __restrict__ xim,
        const float* __restrict__ g, const float* __restrict__ b,
        unsigned short* __restrict__ xpad) {
    int gid = blockIdx.x * 256 + threadIdx.x;   // t*4096 + px
    int t = gid >> 12, px = gid & 4095;
    int row = px >> 6, col = px & 63;
    const float* pr = xre + (size_t)t * DD * PX + px;
    const float* pi = xim + (size_t)t * DD * PX + px;
    float s = 0.f, ss = 0.f;
    #pragma unroll
    for (int d = 0; d < DD; ++d) {
        float vr = pr[d * PX], vi = pi[d * PX];
        s += vr + vi; ss += vr * vr + vi * vi;
    }
    float m = s * (1.f / 64.f);
    float var = ss * (1.f / 64.f) - m * m;
    float rs = rsqrtf(var + 1e-5f);
    unsigned short* o = xpad + ((size_t)t * PPX + (row + 1) * PW + (col + 1)) * 64;
    #pragma unroll
    for (int j = 0; j < 8; ++j) {
        short8v v8;
        #pragma unroll
        for (int dd = 0; dd < 8; ++dd) {
            int ch = j * 8 + dd;
            float v = (ch < 32) ? (pr[ch * PX] - m) * rs * g[ch] + b[ch]
                                : (pi[(ch - 32) * PX] - m) * rs * g[ch] + b[ch];
            v8[dd] = (short)f2b(v);
        }
        *(short8v*)&o[j * 8] = v8;
    }
}

// ---------------- K0: prep — weights bf16/transpose/swizzle + xpad halo -----
__global__ __launch_bounds__(256) void k0_prep(
        const float* __restrict__ w1, const float* __restrict__ w2,
        const float* __restrict__ convw,
        const float* __restrict__ encre, const float* __restrict__ encim,
        const float* __restrict__ decre, const float* __restrict__ decim,
        unsigned short* __restrict__ w1t, unsigned short* __restrict__ w2t,
        unsigned short* __restrict__ w9t,
        unsigned short* __restrict__ benct, unsigned short* __restrict__ bdect,
        unsigned short* __restrict__ xpad) {
    int gid = blockIdx.x * 256 + threadIdx.x;
    if (gid < 32768) {
        int idx = gid;
        int e = idx >> 13, r = idx & 8191;
        int f = r >> 6, p = r & 63;
        int c = (p & 7) + 8 * ((p >> 3) ^ (f & 7));
        w1t[idx] = f2b(w1[((size_t)e * 64 + c) * 128 + f]);
    } else if (gid < 65536) {
        int idx = gid - 32768;
        int e = idx >> 13, r = idx & 8191;
        int n = r >> 7, p = r & 127;
        int f = (p & 7) + 8 * ((p >> 3) ^ (n & 7));
        w2t[idx] = f2b(w2[((size_t)e * 128 + f) * 64 + n]);
    } else if (gid < 102400) {
        int idx = gid - 65536;
        int tap = idx >> 12, rem = idx & 4095;
        int n = rem >> 6, p = rem & 63;
        int k = (p & 7) + 8 * ((p >> 3) ^ (n & 7));
        w9t[idx] = f2b(convw[((size_t)n * 64 + k) * 9 + tap]);
    } else if (gid < 110592) {
        int idx = gid - 102400;
        const float* Rr = (idx < 4096) ? encre : decre;
        const float* Ri = (idx < 4096) ? encim : decim;
        unsigned short* dst = (idx < 4096) ? benct : bdect;
        idx &= 4095;
        int n = idx >> 6, p = idx & 63;
        int k = (p & 7) + 8 * ((p >> 3) ^ (n & 7));
        float v;
        if (n < 32) v = (k < 32) ? Rr[k * 32 + n] : -Ri[(k - 32) * 32 + n];
        else        v = (k < 32) ? Ri[k * 32 + (n - 32)] : Rr[(k - 32) * 32 + (n - 32)];
        dst[idx] = f2b(v);
    } else if (gid < 110592 + 32 * 260) {
        int idx = gid - 110592;                 // halo zeroing
        int im = idx / 260, h = idx % 260;
        int row, col;
        if (h < 66)       { row = 0;  col = h; }
        else if (h < 132) { row = 65; col = h - 66; }
        else { int hh = h - 132; row = 1 + (hh >> 1); col = (hh & 1) * 65; }
        unsigned short* p = xpad + ((size_t)im * PPX + row * PW + col) * 64;
        short8v z = (short8v)0;
        #pragma unroll
        for (int j = 0; j < 8; ++j) *(short8v*)&p[j * 8] = z;
    }
}

// ---------------- K2: 3x3 conv 64->64 as 9-tap implicit GEMM (bf16 MFMA) ----
__global__ __launch_bounds__(256, 2) void k2_conv(
        const unsigned short* __restrict__ xpad,
        const unsigned short* __restrict__ w9t,
        const float* __restrict__ bias, float* __restrict__ xs) {
    __shared__ __align__(16) unsigned short wst[36864];   // 9 taps x 64oc x 64ic swz
    int tid = threadIdx.x;
    int bid = blockIdx.x;
    int lb = (bid & 7) * 64 + (bid >> 3);   // bijective (512 % 8 == 0)
    int t = lb >> 4, rg = lb & 15;
    int lane = tid & 63, wv = tid >> 6;
    int l15 = lane & 15, g = lane >> 4;
    #pragma unroll
    for (int i = 0; i < 18; ++i) {
        int idx = i * 256 + tid;
        *(short8v*)&wst[idx * 8] = *(const short8v*)&w9t[idx * 8];
    }
    __syncthreads();
    int r = rg * 4 + wv;
    const unsigned short* xb = xpad + (size_t)t * PPX * 64;
    f32x4 acc[4][4];
    #pragma unroll
    for (int m = 0; m < 4; ++m)
        #pragma unroll
        for (int nt = 0; nt < 4; ++nt) acc[m][nt] = (f32x4)0.f;

    #pragma unroll
    for (int kh = 0; kh < 3; ++kh) {
        #pragma unroll
        for (int kw = 0; kw < 3; ++kw) {
            int tap = kh * 3 + kw;
            #pragma unroll
            for (int kc = 0; kc < 2; ++kc) {
                short8v a[4];
                #pragma unroll
                for (int m = 0; m < 4; ++m) {
                    int pcol = m * 16 + l15 + kw;
                    a[m] = *(const short8v*)&xb[((size_t)(r + kh) * PW + pcol) * 64 + kc * 32 + g * 8];
                }
                #pragma unroll
                for (int nt = 0; nt < 4; ++nt) {
                    int n = nt * 16 + l15;
                    short8v bf = *(const short8v*)&wst[tap * 4096 + n * 64 + ((kc * 4 + g) ^ (n & 7)) * 8];
                    #pragma unroll
                    for (int m = 0; m < 4; ++m)
                        acc[m][nt] = __builtin_amdgcn_mfma_f32_16x16x32_bf16(a[m], bf, acc[m][nt], 0, 0, 0);
                }
            }
        }
    }
    float* dst = xs + ((size_t)t * PX + r * 64) * 64;
    #pragma unroll
    for (int nt = 0; nt < 4; ++nt) {
        float bo = bias[nt * 16 + l15];
        #pragma unroll
        for (int m = 0; m < 4; ++m) {
            #pragma unroll
            for (int reg = 0; reg < 4; ++reg) {
                int tok = m * 16 + g * 4 + reg;
                dst[(size_t)tok * 64 + nt * 16 + l15] = acc[m][nt][reg] + bo;
            }
        }
    }
}

// ---------------- K3: per-(t,c) spatial PARTIAL sums, 512 blocks ------------
// block = (t, 16-slice of 256 px). Final 16-way reduce happens in k4.
__global__ __launch_bounds__(256) void k3_mean(
        const float* __restrict__ xs, float* __restrict__ mpart) {
    __shared__ f32x4 red[256];
    int t = blockIdx.x >> 4, sl = blockIdx.x & 15;
    int c4 = threadIdx.x & 15, q = threadIdx.x >> 4;
    const float* base = xs + ((size_t)t * PX + sl * 256) * 64 + c4 * 4;
    f32x4 s = (f32x4)0.f;
    for (int px = q; px < 256; px += 16)
        s += *(const f32x4*)&base[(size_t)px * 64];
    red[threadIdx.x] = s;
    __syncthreads();
    for (int st = 8; st > 0; st >>= 1) {
        if (q < st) red[q * 16 + c4] += red[(q + st) * 16 + c4];
        __syncthreads();
    }
    if (q == 0)
        *(f32x4*)&mpart[((size_t)t * 16 + sl) * 64 + c4 * 4] = red[c4];
}

// ---------------- K4: mean finalize + decay/forcing tables + flux scan ------
__global__ __launch_bounds__(256) void k4_ops(
        const float* __restrict__ dt, const float* __restrict__ lam_re,
        const float* __restrict__ lam_im, const float* __restrict__ alpha,
        const float* __restrict__ wre, const float* __restrict__ wim,
        const float* __restrict__ mpart, float* __restrict__ tabs,
        float* __restrict__ outflux) {
    __shared__ float meanl[2048];
    int tid = threadIdx.x;
    // finalize mean: reduce 16 slice-partials per (t,c)
    for (int idx = tid; idx < 2048; idx += 256) {
        int t = idx >> 6, c = idx & 63;
        float s = 0.f;
        #pragma unroll
        for (int p = 0; p < 16; ++p) s += mpart[((size_t)t * 16 + p) * 64 + c];
        meanl[idx] = s * (1.f / 4096.f);
    }
    __syncthreads();
    for (int idx = tid; idx < 1024; idx += 256) {
        int t = idx >> 5, d = idx & 31;
        float x = lam_re[d];
        float sp = (x > 0.f) ? x + log1pf(expf(-x)) : log1pf(expf(x));
        float lr = -sp, li = lam_im[d];
        float dtv = dt[t];
        float er = expf(lr * dtv);
        float dr = er * cosf(li * dtv);
        float di = er * sinf(li * dtv);
        float den = lr * lr + li * li;
        float fr = ((dr - 1.f) * lr + di * li) / den;
        float fi = (di * lr - (dr - 1.f) * li) / den;
        tabs[idx] = dr; tabs[1024 + idx] = di;
        tabs[2048 + idx] = fr; tabs[3072 + idx] = fi;
    }
    if (tid < 32) {
        int d = tid;
        float a = 1.f / (1.f + expf(-alpha[d]));
        float yr = 0.f, yi = 0.f;
        for (int t = 0; t < 32; ++t) {
            float xr = 0.f, xi = 0.f;
            for (int k = 0; k < 32; ++k) {
                float mr = meanl[t * 64 + k], mi = meanl[t * 64 + 32 + k];
                float wr = wre[k * 32 + d], wi = wim[k * 32 + d];
                xr += mr * wr - mi * wi;
                xi += mr * wi + mi * wr;
            }
            yr = a * yr + xr; yi = a * yi + xi;
        }
        outflux[d] = yr; outflux[32 + d] = yi;
    }
}

// ---------------- K5a/K5c: token GEMM, 2 tiles (128 tok) per block ----------
template<bool FORCING>
__global__ __launch_bounds__(256) void k5_gemm(
        const float* A, const unsigned short* __restrict__ Bt,
        const float* __restrict__ tabs, float* O) {
    __shared__ __align__(16) unsigned short fA[64 * 64];
    __shared__ __align__(16) unsigned short bst[64 * 64];
    int tid = threadIdx.x;
    int lane = tid & 63, wv = tid >> 6;
    int l15 = lane & 15, g = lane >> 4;
    int row0 = wv * 16 + l15;
    int rowb = wv * 16 + g * 4;
    #pragma unroll
    for (int i = 0; i < 2; ++i)
        *(short8v*)&bst[(i * 256 + tid) * 8] = *(const short8v*)&Bt[(i * 256 + tid) * 8];

    #pragma unroll
    for (int tile = 0; tile < 2; ++tile) {
        size_t tok0 = ((size_t)blockIdx.x * 2 + tile) * 64;
        if (tile) __syncthreads();   // prev tile's fA fragment reads done
        #pragma unroll
        for (int r = 0; r < 16; ++r) {
            int idx = r * 256 + tid;
            int tok = idx >> 6, c = idx & 63;
            fA[tok * 64 + (c & 7) + 8 * ((c >> 3) ^ (tok & 7))] = f2b(A[(tok0 + tok) * 64 + c]);
        }
        __syncthreads();   // fA (+bst on tile 0) ready
        short8v a1[2];
        #pragma unroll
        for (int st = 0; st < 2; ++st)
            a1[st] = *(const short8v*)&fA[row0 * 64 + (((st * 4 + g) ^ (row0 & 7))) * 8];
        f32x4 eo[4];
        #pragma unroll
        for (int i = 0; i < 4; ++i) eo[i] = (f32x4)0.f;
        #pragma unroll
        for (int st = 0; st < 2; ++st) {
            #pragma unroll
            for (int nt = 0; nt < 4; ++nt) {
                int n = nt * 16 + l15;
                short8v b = *(const short8v*)&bst[n * 64 + (((st * 4 + g) ^ (n & 7))) * 8];
                eo[nt] = __builtin_amdgcn_mfma_f32_16x16x32_bf16(a1[st], b, eo[nt], 0, 0, 0);
            }
        }
        if (FORCING) {
            int t = (int)(tok0 >> 12);
            #pragma unroll
            for (int p = 0; p < 2; ++p) {
                int d = p * 16 + l15;
                float fr = tabs[2048 + t * 32 + d], fi = tabs[3072 + t * 32 + d];
                #pragma unroll
                for (int r = 0; r < 4; ++r) {
                    float ur = eo[p][r], ui = eo[p + 2][r];
                    eo[p][r]     = ur * fr - ui * fi;
                    eo[p + 2][r] = ur * fi + ui * fr;
                }
            }
        }
        #pragma unroll
        for (int nt = 0; nt < 4; ++nt) {
            int n = nt * 16 + l15;
            #pragma unroll
            for (int r = 0; r < 4; ++r)
                O[(tok0 + rowb + r) * 64 + n] = eo[nt][r];
        }
    }
}

// ---------------- K5b: time scan + noise, pure streaming (in-place) ---------
__global__ __launch_bounds__(256) void k5b_scan(
        float* U, const float* __restrict__ tabs, const float* __restrict__ dt,
        const float* __restrict__ eps_re, const float* __restrict__ eps_im) {
    int gid = blockIdx.x * 256 + threadIdx.x;   // px*32 + d
    int px = gid >> 5, d = gid & 31;
    float Yr = 0.f, Yi = 0.f;
    for (int t = 0; t < TT; ++t) {
        size_t tok = (size_t)t * PX + px;
        float usr = U[tok * 64 + d], usi = U[tok * 64 + 32 + d];
        float dr = tabs[t * 32 + d], di = tabs[1024 + t * 32 + d];
        float nYr = dr * Yr - di * Yi + usr;
        float nYi = dr * Yi + di * Yr + usi;
        Yr = nYr; Yi = nYi;
        float s = 0.01f * sqrtf(dt[t]);
        size_t ei = tok * 32 + d;
        float epr = eps_re[ei], epi = eps_im[ei];
        U[tok * 64 + d]      = Yr + s * (Yr * epr - Yi * epi);
        U[tok * 64 + 32 + d] = Yi + s * (Yr * epi + Yi * epr);
    }
}

// ---------------- K6: LN2 + gated MoE MLP — R9/R14-proven (96 µs) -----------
__global__ __launch_bounds__(256, 4) void k6_moe(
        const float* __restrict__ xo,
        const float* __restrict__ g2, const float* __restrict__ b2ln,
        const float* __restrict__ wg,
        const unsigned short* __restrict__ w1t, const float* __restrict__ b1,
        const unsigned short* __restrict__ w2t, const float* __restrict__ b2m,
        const float* __restrict__ xre, const float* __restrict__ xim,
        float* __restrict__ out) {
    __shared__ __align__(16) float hdl[64 * 65];           // H bf16[64][128] / delta f32[64][65]
    __shared__ __align__(16) unsigned short wst[8192];     // one weight matrix
    __shared__ float wgl[256];
    unsigned short* H = (unsigned short*)hdl;

    int tid = threadIdx.x;
    int lane = tid & 63;
    int wv = tid >> 6;
    int l15 = lane & 15, g = lane >> 4;
    int t = blockIdx.x >> 6;
    int px0 = (blockIdx.x & 63) * 64;
    int tok = wv * 16 + l15;
    int tsw = tok & 7;

    wgl[tid] = wg[tid];

    float f[16];
    {
        const float* src = xo + ((size_t)t * PX + px0 + tok) * 64 + g * 8;
        #pragma unroll
        for (int st = 0; st < 2; ++st) {
            float4 v0 = *(const float4*)&src[st * 32];
            float4 v1 = *(const float4*)&src[st * 32 + 4];
            f[st*8+0]=v0.x; f[st*8+1]=v0.y; f[st*8+2]=v0.z; f[st*8+3]=v0.w;
            f[st*8+4]=v1.x; f[st*8+5]=v1.y; f[st*8+6]=v1.z; f[st*8+7]=v1.w;
        }
    }
    float s = 0.f, ss = 0.f;
    #pragma unroll
    for (int i = 0; i < 16; ++i) { s += f[i]; ss += f[i] * f[i]; }
    s += __shfl_xor(s, 16); ss += __shfl_xor(ss, 16);
    s += __shfl_xor(s, 32); ss += __shfl_xor(ss, 32);
    float m = s * (1.f / 64.f);
    float rs = rsqrtf(ss * (1.f / 64.f) - m * m + 1e-5f);
    #pragma unroll
    for (int st = 0; st < 2; ++st) {
        int c0 = st * 32 + g * 8;
        float4 gv0 = *(const float4*)&g2[c0],   gv1 = *(const float4*)&g2[c0 + 4];
        float4 bv0 = *(const float4*)&b2ln[c0], bv1 = *(const float4*)&b2ln[c0 + 4];
        f[st*8+0] = (f[st*8+0]-m)*rs*gv0.x + bv0.x;
        f[st*8+1] = (f[st*8+1]-m)*rs*gv0.y + bv0.y;
        f[st*8+2] = (f[st*8+2]-m)*rs*gv0.z + bv0.z;
        f[st*8+3] = (f[st*8+3]-m)*rs*gv0.w + bv0.w;
        f[st*8+4] = (f[st*8+4]-m)*rs*gv1.x + bv1.x;
        f[st*8+5] = (f[st*8+5]-m)*rs*gv1.y + bv1.y;
        f[st*8+6] = (f[st*8+6]-m)*rs*gv1.z + bv1.z;
        f[st*8+7] = (f[st*8+7]-m)*rs*gv1.w + bv1.w;
    }
    __syncthreads();   // wgl visible
    float gt[4];
    {
        float g0 = 0.f, g1 = 0.f, g2_ = 0.f, g3 = 0.f;
        #pragma unroll
        for (int st = 0; st < 2; ++st)
            #pragma unroll
            for (int j = 0; j < 8; ++j) {
                int c = st * 32 + g * 8 + j;
                float fv = f[st * 8 + j];
                g0 += fv * wgl[c*4];   g1 += fv * wgl[c*4+1];
                g2_ += fv * wgl[c*4+2]; g3 += fv * wgl[c*4+3];
            }
        g0 += __shfl_xor(g0, 16); g1 += __shfl_xor(g1, 16);
        g2_ += __shfl_xor(g2_, 16); g3 += __shfl_xor(g3, 16);
        g0 += __shfl_xor(g0, 32); g1 += __shfl_xor(g1, 32);
        g2_ += __shfl_xor(g2_, 32); g3 += __shfl_xor(g3, 32);
        float mx = fmaxf(fmaxf(g0, g1), fmaxf(g2_, g3));
        float e0 = expf(g0-mx), e1 = expf(g1-mx), e2 = expf(g2_-mx), e3 = expf(g3-mx);
        float inv = 1.f / (e0 + e1 + e2 + e3);
        gt[0] = e0*inv; gt[1] = e1*inv; gt[2] = e2*inv; gt[3] = e3*inv;
    }
    short8v bf1[2];
    #pragma unroll
    for (int st = 0; st < 2; ++st)
        #pragma unroll
        for (int j = 0; j < 8; ++j)
            bf1[st][j] = (short)f2b(f[st * 8 + j]);

    f32x4 dacc[4];
    #pragma unroll
    for (int i = 0; i < 4; ++i) dacc[i] = (f32x4)0.f;

    for (int e = 0; e < 4; ++e) {
        __syncthreads();   // prev GEMM2 done reading wst/H
        {
            const short8v* gp = (const short8v*)(w1t + (size_t)e * 8192);
            #pragma unroll
            for (int i = 0; i < 4; ++i)
                *(short8v*)&wst[(i * 256 + tid) * 8] = gp[i * 256 + tid];
        }
        __syncthreads();   // w1e ready
        f32x4 h[8];
        #pragma unroll
        for (int i = 0; i < 8; ++i) h[i] = (f32x4)0.f;
        #pragma unroll
        for (int st = 0; st < 2; ++st) {
            #pragma unroll
            for (int ft = 0; ft < 8; ++ft) {
                int fi = ft * 16 + l15;
                short8v a = *(const short8v*)&wst[fi * 64 + (((st * 4 + g) ^ (fi & 7))) * 8];
                h[ft] = __builtin_amdgcn_mfma_f32_16x16x32_bf16(a, bf1[st], h[ft], 0, 0, 0);
            }
        }
        #pragma unroll
        for (int ft = 0; ft < 8; ++ft) {
            int f0 = ft * 16 + g * 4;
            float4 bb = *(const float4*)&b1[e * 128 + f0];
            unsigned short p0 = f2b(gelu_fast(h[ft][0] + bb.x));
            unsigned short p1 = f2b(gelu_fast(h[ft][1] + bb.y));
            unsigned short p2 = f2b(gelu_fast(h[ft][2] + bb.z));
            unsigned short p3 = f2b(gelu_fast(h[ft][3] + bb.w));
            unsigned long long pk = (unsigned long long)p0 | ((unsigned long long)p1 << 16)
                                  | ((unsigned long long)p2 << 32) | ((unsigned long long)p3 << 48);
            *(unsigned long long*)&H[tok * 128 + (f0 & 7) + 8 * ((f0 >> 3) ^ tsw)] = pk;
        }
        __syncthreads();   // GEMM1 wst reads done + H complete
        {
            const short8v* gp = (const short8v*)(w2t + (size_t)e * 8192);
            #pragma unroll
            for (int i = 0; i < 4; ++i)
                *(short8v*)&wst[(i * 256 + tid) * 8] = gp[i * 256 + tid];
        }
        __syncthreads();   // w2e ready
        f32x4 eo[4];
        #pragma unroll
        for (int i = 0; i < 4; ++i) eo[i] = (f32x4)0.f;
        #pragma unroll
        for (int st = 0; st < 4; ++st) {
            short8v bh = *(const short8v*)&H[tok * 128 + (((st * 4 + g) ^ tsw)) * 8];
            #pragma unroll
            for (int nt = 0; nt < 4; ++nt) {
                int n = nt * 16 + l15;
                short8v a = *(const short8v*)&wst[n * 128 + (((st * 4 + g) ^ (n & 7))) * 8];
                eo[nt] = __builtin_amdgcn_mfma_f32_16x16x32_bf16(a, bh, eo[nt], 0, 0, 0);
            }
        }
        float ge = gt[e];
        #pragma unroll
        for (int nt = 0; nt < 4; ++nt) {
            int n0 = nt * 16 + g * 4;
            float4 bb = *(const float4*)&b2m[e * 64 + n0];
            dacc[nt][0] += ge * (eo[nt][0] + bb.x);
            dacc[nt][1] += ge * (eo[nt][1] + bb.y);
            dacc[nt][2] += ge * (eo[nt][2] + bb.z);
            dacc[nt][3] += ge * (eo[nt][3] + bb.w);
        }
    }
    __syncthreads();   // all H reads done; reuse hdl as f32 delta [64][65]
    float* dl = hdl;
    #pragma unroll
    for (int nt = 0; nt < 4; ++nt) {
        int n0 = nt * 16 + g * 4;
        #pragma unroll
        for (int r = 0; r < 4; ++r)
            dl[tok * 65 + n0 + r] = dacc[nt][r];
    }
    __syncthreads();
    #pragma unroll
    for (int st = 0; st < 2; ++st) {
        const float* xsrc = (st == 0) ? xre : xim;
        float* osrc = out + (st == 0 ? 0 : (size_t)4194304);
        #pragma unroll
        for (int j = 0; j < 8; ++j) {
            int c = st * 32 + g * 8 + j;
            float val = b2f((unsigned short)bf1[st][j]) + dl[tok * 65 + c];
            size_t xi_ = ((size_t)t * 32 + (c & 31)) * PX + px0 + tok;
            osrc[xi_] = val + xsrc[xi_];
        }
    }
}

extern "C" void kernel_launch(void* const* d_in, const int* in_sizes, int n_in,
                              void* d_out, int out_size, void* d_ws, size_t ws_size,
                              hipStream_t stream) {
    const float* xre   = (const float*)d_in[0];
    const float* xim   = (const float*)d_in[1];
    const float* dt    = (const float*)d_in[2];
    const float* epsre = (const float*)d_in[3];
    const float* epsim = (const float*)d_in[4];
    const float* ln1g  = (const float*)d_in[5];
    const float* ln1b  = (const float*)d_in[6];
    const float* ln2g  = (const float*)d_in[7];
    const float* ln2b  = (const float*)d_in[8];
    const float* convw = (const float*)d_in[9];
    const float* convb = (const float*)d_in[10];
    const float* encre = (const float*)d_in[11];
    const float* encim = (const float*)d_in[12];
    const float* decre = (const float*)d_in[13];
    const float* decim = (const float*)d_in[14];
    const float* lamre = (const float*)d_in[15];
    const float* lamim = (const float*)d_in[16];
    const float* alpha = (const float*)d_in[17];
    const float* fwre  = (const float*)d_in[18];
    const float* fwim  = (const float*)d_in[19];
    const float* wg    = (const float*)d_in[20];
    const float* w1    = (const float*)d_in[21];
    const float* b1    = (const float*)d_in[22];
    const float* w2    = (const float*)d_in[23];
    const float* b2    = (const float*)d_in[24];
    float* out = (float*)d_out;

    float* ws = (float*)d_ws;
    unsigned short* xpad = (unsigned short*)ws;   // region A: xpad bf16 then xo f32
    float* xo   = ws;
    float* xs   = ws + 8388608;         // NHWC f32: conv out -> U (in-place) -> W
    float* tabs = ws + 16779264;        // 4096 floats
    unsigned short* w1t = (unsigned short*)(ws + 16783360);
    unsigned short* w2t = w1t + 32768;
    unsigned short* w9t = w2t + 32768;
    unsigned short* benct = w9t + 36864;
    unsigned short* bdect = benct + 4096;
    float* mpart = ws + 16783360 + 55296;   // 512*64 floats (after weight bufs)

    k0_prep<<<465, 256, 0, stream>>>(w1, w2, convw, encre, encim, decre, decim,
                                     w1t, w2t, w9t, benct, bdect, xpad);
    k1_ln1<<<512, 256, 0, stream>>>(xre, xim, ln1g, ln1b, xpad);
    k2_conv<<<512, 256, 0, stream>>>(xpad, w9t, convb, xs);
    k3_mean<<<512, 256, 0, stream>>>(xs, mpart);
    k4_ops<<<1, 256, 0, stream>>>(dt, lamre, lamim, alpha, fwre, fwim, mpart,
                                  tabs, out + 8388608);
    k5_gemm<true><<<1024, 256, 0, stream>>>(xs, benct, tabs, xs);   // u*forcing
    k5b_scan<<<512, 256, 0, stream>>>(xs, tabs, dt, epsre, epsim);  // scan+noise
    k5_gemm<false><<<1024, 256, 0, stream>>>(xs, bdect, tabs, xo);  // dec
    k6_moe<<<2048, 256, 0, stream>>>(xo, ln2g, ln2b, wg, w1t, b1, w2t, b2,
                                     xre, xim, out);
}

// Round 20
// 189.774 us; speedup vs baseline: 1.4286x; 1.0405x over previous
//
#include <hip/hip_runtime.h>
#include <math.h>

#define PX 4096   // 64*64
#define TT 32
#define DD 32
#define CC 64     // 2*D
#define PW 66     // padded width
#define PPX 4356  // 66*66

typedef __attribute__((ext_vector_type(8))) short short8v;
typedef __attribute__((ext_vector_type(4))) float f32x4;

__device__ __forceinline__ float gelu_fast(float x) {
    float u = x * x;
    float a = x * (1.5957691216057308f + 0.07135481627f * u);
    return x / (1.0f + __expf(-a));
}

__device__ __forceinline__ unsigned short f2b(float x) {
    union { float f; unsigned u; } v; v.f = x;
    unsigned r = v.u + 0x7FFF + ((v.u >> 16) & 1);
    return (unsigned short)(r >> 16);
}

__device__ __forceinline__ float b2f(unsigned short b) {
    union { unsigned u; float f; } v; v.u = ((unsigned)b) << 16;
    return v.f;
}

// ---------------- K1: LN1 (64ch) fused -> padded bf16 NHWC ------------------
__global__ __launch_bounds__(256) void k1_ln1(
        const float* __restrict__ xre, const float* __restrict__ xim,
        const float* __restrict__ g, const float* __restrict__ b,
        unsigned short* __restrict__ xpad) {
    int gid = blockIdx.x * 256 + threadIdx.x;   // t*4096 + px
    int t = gid >> 12, px = gid & 4095;
    int row = px >> 6, col = px & 63;
    const float* pr = xre + (size_t)t * DD * PX + px;
    const float* pi = xim + (size_t)t * DD * PX + px;
    float s = 0.f, ss = 0.f;
    #pragma unroll
    for (int d = 0; d < DD; ++d) {
        float vr = pr[d * PX], vi = pi[d * PX];
        s += vr + vi; ss += vr * vr + vi * vi;
    }
    float m = s * (1.f / 64.f);
    float var = ss * (1.f / 64.f) - m * m;
    float rs = rsqrtf(var + 1e-5f);
    unsigned short* o = xpad + ((size_t)t * PPX + (row + 1) * PW + (col + 1)) * 64;
    #pragma unroll
    for (int j = 0; j < 8; ++j) {
        short8v v8;
        #pragma unroll
        for (int dd = 0; dd < 8; ++dd) {
            int ch = j * 8 + dd;
            float v = (ch < 32) ? (pr[ch * PX] - m) * rs * g[ch] + b[ch]
                                : (pi[(ch - 32) * PX] - m) * rs * g[ch] + b[ch];
            v8[dd] = (short)f2b(v);
        }
        *(short8v*)&o[j * 8] = v8;
    }
}

// ------- K0: prep — weights bf16/transpose/swizzle + xpad halo + tabs -------
__global__ __launch_bounds__(256) void k0_prep(
        const float* __restrict__ w1, const float* __restrict__ w2,
        const float* __restrict__ convw,
        const float* __restrict__ encre, const float* __restrict__ encim,
        const float* __restrict__ decre, const float* __restrict__ decim,
        const float* __restrict__ dt, const float* __restrict__ lam_re,
        const float* __restrict__ lam_im,
        unsigned short* __restrict__ w1t, unsigned short* __restrict__ w2t,
        unsigned short* __restrict__ w9t,
        unsigned short* __restrict__ benct, unsigned short* __restrict__ bdect,
        unsigned short* __restrict__ xpad, float* __restrict__ tabs) {
    int gid = blockIdx.x * 256 + threadIdx.x;
    if (gid < 32768) {
        int idx = gid;
        int e = idx >> 13, r = idx & 8191;
        int f = r >> 6, p = r & 63;
        int c = (p & 7) + 8 * ((p >> 3) ^ (f & 7));
        w1t[idx] = f2b(w1[((size_t)e * 64 + c) * 128 + f]);
    } else if (gid < 65536) {
        int idx = gid - 32768;
        int e = idx >> 13, r = idx & 8191;
        int n = r >> 7, p = r & 127;
        int f = (p & 7) + 8 * ((p >> 3) ^ (n & 7));
        w2t[idx] = f2b(w2[((size_t)e * 128 + f) * 64 + n]);
    } else if (gid < 102400) {
        int idx = gid - 65536;
        int tap = idx >> 12, rem = idx & 4095;
        int n = rem >> 6, p = rem & 63;
        int k = (p & 7) + 8 * ((p >> 3) ^ (n & 7));
        w9t[idx] = f2b(convw[((size_t)n * 64 + k) * 9 + tap]);
    } else if (gid < 110592) {
        int idx = gid - 102400;
        const float* Rr = (idx < 4096) ? encre : decre;
        const float* Ri = (idx < 4096) ? encim : decim;
        unsigned short* dst = (idx < 4096) ? benct : bdect;
        idx &= 4095;
        int n = idx >> 6, p = idx & 63;
        int k = (p & 7) + 8 * ((p >> 3) ^ (n & 7));
        float v;
        if (n < 32) v = (k < 32) ? Rr[k * 32 + n] : -Ri[(k - 32) * 32 + n];
        else        v = (k < 32) ? Ri[k * 32 + (n - 32)] : Rr[(k - 32) * 32 + (n - 32)];
        dst[idx] = f2b(v);
    } else if (gid < 118912) {
        int idx = gid - 110592;                 // halo zeroing
        int im = idx / 260, h = idx % 260;
        int row, col;
        if (h < 66)       { row = 0;  col = h; }
        else if (h < 132) { row = 65; col = h - 66; }
        else { int hh = h - 132; row = 1 + (hh >> 1); col = (hh & 1) * 65; }
        unsigned short* p = xpad + ((size_t)im * PPX + row * PW + col) * 64;
        short8v z = (short8v)0;
        #pragma unroll
        for (int j = 0; j < 8; ++j) *(short8v*)&p[j * 8] = z;
    } else if (gid < 119936) {
        int idx = gid - 118912;                 // tabs (decay/forcing)
        int t = idx >> 5, d = idx & 31;
        float x = lam_re[d];
        float sp = (x > 0.f) ? x + log1pf(expf(-x)) : log1pf(expf(x));
        float lr = -sp, li = lam_im[d];
        float dtv = dt[t];
        float er = expf(lr * dtv);
        float dr = er * cosf(li * dtv);
        float di = er * sinf(li * dtv);
        float den = lr * lr + li * li;
        float fr = ((dr - 1.f) * lr + di * li) / den;
        float fi = (di * lr - (dr - 1.f) * li) / den;
        tabs[idx] = dr; tabs[1024 + idx] = di;
        tabs[2048 + idx] = fr; tabs[3072 + idx] = fi;
    }
}

// ---------------- K2: 3x3 conv 64->64 as 9-tap implicit GEMM (bf16 MFMA) ----
__global__ __launch_bounds__(256, 2) void k2_conv(
        const unsigned short* __restrict__ xpad,
        const unsigned short* __restrict__ w9t,
        const float* __restrict__ bias, float* __restrict__ xs) {
    __shared__ __align__(16) unsigned short wst[36864];   // 9 taps x 64oc x 64ic swz
    int tid = threadIdx.x;
    int bid = blockIdx.x;
    int lb = (bid & 7) * 64 + (bid >> 3);   // bijective (512 % 8 == 0)
    int t = lb >> 4, rg = lb & 15;
    int lane = tid & 63, wv = tid >> 6;
    int l15 = lane & 15, g = lane >> 4;
    #pragma unroll
    for (int i = 0; i < 18; ++i) {
        int idx = i * 256 + tid;
        *(short8v*)&wst[idx * 8] = *(const short8v*)&w9t[idx * 8];
    }
    __syncthreads();
    int r = rg * 4 + wv;
    const unsigned short* xb = xpad + (size_t)t * PPX * 64;
    f32x4 acc[4][4];
    #pragma unroll
    for (int m = 0; m < 4; ++m)
        #pragma unroll
        for (int nt = 0; nt < 4; ++nt) acc[m][nt] = (f32x4)0.f;

    #pragma unroll
    for (int kh = 0; kh < 3; ++kh) {
        #pragma unroll
        for (int kw = 0; kw < 3; ++kw) {
            int tap = kh * 3 + kw;
            #pragma unroll
            for (int kc = 0; kc < 2; ++kc) {
                short8v a[4];
                #pragma unroll
                for (int m = 0; m < 4; ++m) {
                    int pcol = m * 16 + l15 + kw;
                    a[m] = *(const short8v*)&xb[((size_t)(r + kh) * PW + pcol) * 64 + kc * 32 + g * 8];
                }
                #pragma unroll
                for (int nt = 0; nt < 4; ++nt) {
                    int n = nt * 16 + l15;
                    short8v bf = *(const short8v*)&wst[tap * 4096 + n * 64 + ((kc * 4 + g) ^ (n & 7)) * 8];
                    #pragma unroll
                    for (int m = 0; m < 4; ++m)
                        acc[m][nt] = __builtin_amdgcn_mfma_f32_16x16x32_bf16(a[m], bf, acc[m][nt], 0, 0, 0);
                }
            }
        }
    }
    float* dst = xs + ((size_t)t * PX + r * 64) * 64;
    #pragma unroll
    for (int nt = 0; nt < 4; ++nt) {
        float bo = bias[nt * 16 + l15];
        #pragma unroll
        for (int m = 0; m < 4; ++m) {
            #pragma unroll
            for (int reg = 0; reg < 4; ++reg) {
                int tok = m * 16 + g * 4 + reg;
                dst[(size_t)tok * 64 + nt * 16 + l15] = acc[m][nt][reg] + bo;
            }
        }
    }
}

// ---------------- K4b: mean finalize (32 partials/t) + flux scan ------------
__global__ __launch_bounds__(256) void k4_flux(
        const float* __restrict__ alpha,
        const float* __restrict__ wre, const float* __restrict__ wim,
        const float* __restrict__ mpart, float* __restrict__ outflux) {
    __shared__ float meanl[2048];
    int tid = threadIdx.x;
    for (int idx = tid; idx < 2048; idx += 256) {
        int t = idx >> 6, c = idx & 63;
        float s = 0.f;
        #pragma unroll
        for (int p = 0; p < 32; ++p) s += mpart[((size_t)t * 32 + p) * 64 + c];
        meanl[idx] = s * (1.f / 4096.f);
    }
    __syncthreads();
    if (tid < 32) {
        int d = tid;
        float a = 1.f / (1.f + expf(-alpha[d]));
        float yr = 0.f, yi = 0.f;
        for (int t = 0; t < 32; ++t) {
            float xr = 0.f, xi = 0.f;
            for (int k = 0; k < 32; ++k) {
                float mr = meanl[t * 64 + k], mi = meanl[t * 64 + 32 + k];
                float wr = wre[k * 32 + d], wi = wim[k * 32 + d];
                xr += mr * wr - mi * wi;
                xi += mr * wi + mi * wr;
            }
            yr = a * yr + xr; yi = a * yi + xi;
        }
        outflux[d] = yr; outflux[32 + d] = yi;
    }
}

// ---------------- K5a/K5c: token GEMM, 2 tiles (128 tok) per block ----------
// FORCING variant also accumulates per-channel partial sums of A (the conv
// output) into mpart[1024][64] — replaces the old k3_mean kernel.
template<bool FORCING>
__global__ __launch_bounds__(256) void k5_gemm(
        const float* A, const unsigned short* __restrict__ Bt,
        const float* __restrict__ tabs, float* O, float* __restrict__ mpart) {
    __shared__ __align__(16) unsigned short fA[64 * 64];
    __shared__ __align__(16) unsigned short bst[64 * 64];
    __shared__ float red[256];
    int tid = threadIdx.x;
    int lane = tid & 63, wv = tid >> 6;
    int l15 = lane & 15, g = lane >> 4;
    int row0 = wv * 16 + l15;
    int rowb = wv * 16 + g * 4;
    #pragma unroll
    for (int i = 0; i < 2; ++i)
        *(short8v*)&bst[(i * 256 + tid) * 8] = *(const short8v*)&Bt[(i * 256 + tid) * 8];

    float msum = 0.f;
    #pragma unroll
    for (int tile = 0; tile < 2; ++tile) {
        size_t tok0 = ((size_t)blockIdx.x * 2 + tile) * 64;
        if (tile) __syncthreads();   // prev tile's fA fragment reads done
        #pragma unroll
        for (int r = 0; r < 16; ++r) {
            int idx = r * 256 + tid;
            int tok = idx >> 6, c = idx & 63;
            float v = A[(tok0 + tok) * 64 + c];
            if (FORCING) msum += v;
            fA[tok * 64 + (c & 7) + 8 * ((c >> 3) ^ (tok & 7))] = f2b(v);
        }
        __syncthreads();   // fA (+bst on tile 0) ready
        short8v a1[2];
        #pragma unroll
        for (int st = 0; st < 2; ++st)
            a1[st] = *(const short8v*)&fA[row0 * 64 + (((st * 4 + g) ^ (row0 & 7))) * 8];
        f32x4 eo[4];
        #pragma unroll
        for (int i = 0; i < 4; ++i) eo[i] = (f32x4)0.f;
        #pragma unroll
        for (int st = 0; st < 2; ++st) {
            #pragma unroll
            for (int nt = 0; nt < 4; ++nt) {
                int n = nt * 16 + l15;
                short8v b = *(const short8v*)&bst[n * 64 + (((st * 4 + g) ^ (n & 7))) * 8];
                eo[nt] = __builtin_amdgcn_mfma_f32_16x16x32_bf16(a1[st], b, eo[nt], 0, 0, 0);
            }
        }
        if (FORCING) {
            int t = (int)(tok0 >> 12);
            #pragma unroll
            for (int p = 0; p < 2; ++p) {
                int d = p * 16 + l15;
                float fr = tabs[2048 + t * 32 + d], fi = tabs[3072 + t * 32 + d];
                #pragma unroll
                for (int r = 0; r < 4; ++r) {
                    float ur = eo[p][r], ui = eo[p + 2][r];
                    eo[p][r]     = ur * fr - ui * fi;
                    eo[p + 2][r] = ur * fi + ui * fr;
                }
            }
        }
        #pragma unroll
        for (int nt = 0; nt < 4; ++nt) {
            int n = nt * 16 + l15;
            #pragma unroll
            for (int r = 0; r < 4; ++r)
                O[(tok0 + rowb + r) * 64 + n] = eo[nt][r];
        }
    }
    if (FORCING) {
        __syncthreads();          // fA reads done; reuse red
        red[tid] = msum;
        __syncthreads();
        if (tid < 64)
            mpart[(size_t)blockIdx.x * 64 + tid] =
                red[tid] + red[tid + 64] + red[tid + 128] + red[tid + 192];
    }
}

// ---------------- K5b: time scan + noise, pure streaming (in-place) ---------
__global__ __launch_bounds__(256) void k5b_scan(
        float* U, const float* __restrict__ tabs, const float* __restrict__ dt,
        const float* __restrict__ eps_re, const float* __restrict__ eps_im) {
    int gid = blockIdx.x * 256 + threadIdx.x;   // px*32 + d
    int px = gid >> 5, d = gid & 31;
    float Yr = 0.f, Yi = 0.f;
    for (int t = 0; t < TT; ++t) {
        size_t tok = (size_t)t * PX + px;
        float usr = U[tok * 64 + d], usi = U[tok * 64 + 32 + d];
        float dr = tabs[t * 32 + d], di = tabs[1024 + t * 32 + d];
        float nYr = dr * Yr - di * Yi + usr;
        float nYi = dr * Yi + di * Yr + usi;
        Yr = nYr; Yi = nYi;
        float s = 0.01f * sqrtf(dt[t]);
        size_t ei = tok * 32 + d;
        float epr = eps_re[ei], epi = eps_im[ei];
        U[tok * 64 + d]      = Yr + s * (Yr * epr - Yi * epi);
        U[tok * 64 + 32 + d] = Yi + s * (Yr * epi + Yi * epr);
    }
}

// ---------------- K6: LN2 + gated MoE MLP — R9/R14-proven (96 µs) -----------
__global__ __launch_bounds__(256, 4) void k6_moe(
        const float* __restrict__ xo,
        const float* __restrict__ g2, const float* __restrict__ b2ln,
        const float* __restrict__ wg,
        const unsigned short* __restrict__ w1t, const float* __restrict__ b1,
        const unsigned short* __restrict__ w2t, const float* __restrict__ b2m,
        const float* __restrict__ xre, const float* __restrict__ xim,
        float* __restrict__ out) {
    __shared__ __align__(16) float hdl[64 * 65];           // H bf16[64][128] / delta f32[64][65]
    __shared__ __align__(16) unsigned short wst[8192];     // one weight matrix
    __shared__ float wgl[256];
    unsigned short* H = (unsigned short*)hdl;

    int tid = threadIdx.x;
    int lane = tid & 63;
    int wv = tid >> 6;
    int l15 = lane & 15, g = lane >> 4;
    int t = blockIdx.x >> 6;
    int px0 = (blockIdx.x & 63) * 64;
    int tok = wv * 16 + l15;
    int tsw = tok & 7;

    wgl[tid] = wg[tid];

    float f[16];
    {
        const float* src = xo + ((size_t)t * PX + px0 + tok) * 64 + g * 8;
        #pragma unroll
        for (int st = 0; st < 2; ++st) {
            float4 v0 = *(const float4*)&src[st * 32];
            float4 v1 = *(const float4*)&src[st * 32 + 4];
            f[st*8+0]=v0.x; f[st*8+1]=v0.y; f[st*8+2]=v0.z; f[st*8+3]=v0.w;
            f[st*8+4]=v1.x; f[st*8+5]=v1.y; f[st*8+6]=v1.z; f[st*8+7]=v1.w;
        }
    }
    float s = 0.f, ss = 0.f;
    #pragma unroll
    for (int i = 0; i < 16; ++i) { s += f[i]; ss += f[i] * f[i]; }
    s += __shfl_xor(s, 16); ss += __shfl_xor(ss, 16);
    s += __shfl_xor(s, 32); ss += __shfl_xor(ss, 32);
    float m = s * (1.f / 64.f);
    float rs = rsqrtf(ss * (1.f / 64.f) - m * m + 1e-5f);
    #pragma unroll
    for (int st = 0; st < 2; ++st) {
        int c0 = st * 32 + g * 8;
        float4 gv0 = *(const float4*)&g2[c0],   gv1 = *(const float4*)&g2[c0 + 4];
        float4 bv0 = *(const float4*)&b2ln[c0], bv1 = *(const float4*)&b2ln[c0 + 4];
        f[st*8+0] = (f[st*8+0]-m)*rs*gv0.x + bv0.x;
        f[st*8+1] = (f[st*8+1]-m)*rs*gv0.y + bv0.y;
        f[st*8+2] = (f[st*8+2]-m)*rs*gv0.z + bv0.z;
        f[st*8+3] = (f[st*8+3]-m)*rs*gv0.w + bv0.w;
        f[st*8+4] = (f[st*8+4]-m)*rs*gv1.x + bv1.x;
        f[st*8+5] = (f[st*8+5]-m)*rs*gv1.y + bv1.y;
        f[st*8+6] = (f[st*8+6]-m)*rs*gv1.z + bv1.z;
        f[st*8+7] = (f[st*8+7]-m)*rs*gv1.w + bv1.w;
    }
    __syncthreads();   // wgl visible
    float gt[4];
    {
        float g0 = 0.f, g1 = 0.f, g2_ = 0.f, g3 = 0.f;
        #pragma unroll
        for (int st = 0; st < 2; ++st)
            #pragma unroll
            for (int j = 0; j < 8; ++j) {
                int c = st * 32 + g * 8 + j;
                float fv = f[st * 8 + j];
                g0 += fv * wgl[c*4];   g1 += fv * wgl[c*4+1];
                g2_ += fv * wgl[c*4+2]; g3 += fv * wgl[c*4+3];
            }
        g0 += __shfl_xor(g0, 16); g1 += __shfl_xor(g1, 16);
        g2_ += __shfl_xor(g2_, 16); g3 += __shfl_xor(g3, 16);
        g0 += __shfl_xor(g0, 32); g1 += __shfl_xor(g1, 32);
        g2_ += __shfl_xor(g2_, 32); g3 += __shfl_xor(g3, 32);
        float mx = fmaxf(fmaxf(g0, g1), fmaxf(g2_, g3));
        float e0 = expf(g0-mx), e1 = expf(g1-mx), e2 = expf(g2_-mx), e3 = expf(g3-mx);
        float inv = 1.f / (e0 + e1 + e2 + e3);
        gt[0] = e0*inv; gt[1] = e1*inv; gt[2] = e2*inv; gt[3] = e3*inv;
    }
    short8v bf1[2];
    #pragma unroll
    for (int st = 0; st < 2; ++st)
        #pragma unroll
        for (int j = 0; j < 8; ++j)
            bf1[st][j] = (short)f2b(f[st * 8 + j]);

    f32x4 dacc[4];
    #pragma unroll
    for (int i = 0; i < 4; ++i) dacc[i] = (f32x4)0.f;

    for (int e = 0; e < 4; ++e) {
        __syncthreads();   // prev GEMM2 done reading wst/H
        {
            const short8v* gp = (const short8v*)(w1t + (size_t)e * 8192);
            #pragma unroll
            for (int i = 0; i < 4; ++i)
                *(short8v*)&wst[(i * 256 + tid) * 8] = gp[i * 256 + tid];
        }
        __syncthreads();   // w1e ready
        f32x4 h[8];
        #pragma unroll
        for (int i = 0; i < 8; ++i) h[i] = (f32x4)0.f;
        #pragma unroll
        for (int st = 0; st < 2; ++st) {
            #pragma unroll
            for (int ft = 0; ft < 8; ++ft) {
                int fi = ft * 16 + l15;
                short8v a = *(const short8v*)&wst[fi * 64 + (((st * 4 + g) ^ (fi & 7))) * 8];
                h[ft] = __builtin_amdgcn_mfma_f32_16x16x32_bf16(a, bf1[st], h[ft], 0, 0, 0);
            }
        }
        #pragma unroll
        for (int ft = 0; ft < 8; ++ft) {
            int f0 = ft * 16 + g * 4;
            float4 bb = *(const float4*)&b1[e * 128 + f0];
            unsigned short p0 = f2b(gelu_fast(h[ft][0] + bb.x));
            unsigned short p1 = f2b(gelu_fast(h[ft][1] + bb.y));
            unsigned short p2 = f2b(gelu_fast(h[ft][2] + bb.z));
            unsigned short p3 = f2b(gelu_fast(h[ft][3] + bb.w));
            unsigned long long pk = (unsigned long long)p0 | ((unsigned long long)p1 << 16)
                                  | ((unsigned long long)p2 << 32) | ((unsigned long long)p3 << 48);
            *(unsigned long long*)&H[tok * 128 + (f0 & 7) + 8 * ((f0 >> 3) ^ tsw)] = pk;
        }
        __syncthreads();   // GEMM1 wst reads done + H complete
        {
            const short8v* gp = (const short8v*)(w2t + (size_t)e * 8192);
            #pragma unroll
            for (int i = 0; i < 4; ++i)
                *(short8v*)&wst[(i * 256 + tid) * 8] = gp[i * 256 + tid];
        }
        __syncthreads();   // w2e ready
        f32x4 eo[4];
        #pragma unroll
        for (int i = 0; i < 4; ++i) eo[i] = (f32x4)0.f;
        #pragma unroll
        for (int st = 0; st < 4; ++st) {
            short8v bh = *(const short8v*)&H[tok * 128 + (((st * 4 + g) ^ tsw)) * 8];
            #pragma unroll
            for (int nt = 0; nt < 4; ++nt) {
                int n = nt * 16 + l15;
                short8v a = *(const short8v*)&wst[n * 128 + (((st * 4 + g) ^ (n & 7))) * 8];
                eo[nt] = __builtin_amdgcn_mfma_f32_16x16x32_bf16(a, bh, eo[nt], 0, 0, 0);
            }
        }
        float ge = gt[e];
        #pragma unroll
        for (int nt = 0; nt < 4; ++nt) {
            int n0 = nt * 16 + g * 4;
            float4 bb = *(const float4*)&b2m[e * 64 + n0];
            dacc[nt][0] += ge * (eo[nt][0] + bb.x);
            dacc[nt][1] += ge * (eo[nt][1] + bb.y);
            dacc[nt][2] += ge * (eo[nt][2] + bb.z);
            dacc[nt][3] += ge * (eo[nt][3] + bb.w);
        }
    }
    __syncthreads();   // all H reads done; reuse hdl as f32 delta [64][65]
    float* dl = hdl;
    #pragma unroll
    for (int nt = 0; nt < 4; ++nt) {
        int n0 = nt * 16 + g * 4;
        #pragma unroll
        for (int r = 0; r < 4; ++r)
            dl[tok * 65 + n0 + r] = dacc[nt][r];
    }
    __syncthreads();
    #pragma unroll
    for (int st = 0; st < 2; ++st) {
        const float* xsrc = (st == 0) ? xre : xim;
        float* osrc = out + (st == 0 ? 0 : (size_t)4194304);
        #pragma unroll
        for (int j = 0; j < 8; ++j) {
            int c = st * 32 + g * 8 + j;
            float val = b2f((unsigned short)bf1[st][j]) + dl[tok * 65 + c];
            size_t xi_ = ((size_t)t * 32 + (c & 31)) * PX + px0 + tok;
            osrc[xi_] = val + xsrc[xi_];
        }
    }
}

extern "C" void kernel_launch(void* const* d_in, const int* in_sizes, int n_in,
                              void* d_out, int out_size, void* d_ws, size_t ws_size,
                              hipStream_t stream) {
    const float* xre   = (const float*)d_in[0];
    const float* xim   = (const float*)d_in[1];
    const float* dt    = (const float*)d_in[2];
    const float* epsre = (const float*)d_in[3];
    const float* epsim = (const float*)d_in[4];
    const float* ln1g  = (const float*)d_in[5];
    const float* ln1b  = (const float*)d_in[6];
    const float* ln2g  = (const float*)d_in[7];
    const float* ln2b  = (const float*)d_in[8];
    const float* convw = (const float*)d_in[9];
    const float* convb = (const float*)d_in[10];
    const float* encre = (const float*)d_in[11];
    const float* encim = (const float*)d_in[12];
    const float* decre = (const float*)d_in[13];
    const float* decim = (const float*)d_in[14];
    const float* lamre = (const float*)d_in[15];
    const float* lamim = (const float*)d_in[16];
    const float* alpha = (const float*)d_in[17];
    const float* fwre  = (const float*)d_in[18];
    const float* fwim  = (const float*)d_in[19];
    const float* wg    = (const float*)d_in[20];
    const float* w1    = (const float*)d_in[21];
    const float* b1    = (const float*)d_in[22];
    const float* w2    = (const float*)d_in[23];
    const float* b2    = (const float*)d_in[24];
    float* out = (float*)d_out;

    float* ws = (float*)d_ws;
    unsigned short* xpad = (unsigned short*)ws;   // region A: xpad bf16 then xo f32
    float* xo   = ws;
    float* xs   = ws + 8388608;         // NHWC f32: conv out -> U (in-place) -> W
    float* tabs = ws + 16779264;        // 4096 floats
    unsigned short* w1t = (unsigned short*)(ws + 16783360);
    unsigned short* w2t = w1t + 32768;
    unsigned short* w9t = w2t + 32768;
    unsigned short* benct = w9t + 36864;
    unsigned short* bdect = benct + 4096;
    float* mpart = ws + 16783360 + 55296;   // 1024*64 floats

    k0_prep<<<469, 256, 0, stream>>>(w1, w2, convw, encre, encim, decre, decim,
                                     dt, lamre, lamim,
                                     w1t, w2t, w9t, benct, bdect, xpad, tabs);
    k1_ln1<<<512, 256, 0, stream>>>(xre, xim, ln1g, ln1b, xpad);
    k2_conv<<<512, 256, 0, stream>>>(xpad, w9t, convb, xs);
    k5_gemm<true><<<1024, 256, 0, stream>>>(xs, benct, tabs, xs, mpart);   // enc+forcing+mean
    k5b_scan<<<512, 256, 0, stream>>>(xs, tabs, dt, epsre, epsim);         // scan+noise
    k5_gemm<false><<<1024, 256, 0, stream>>>(xs, bdect, tabs, xo, nullptr);// dec
    k4_flux<<<1, 256, 0, stream>>>(alpha, fwre, fwim, mpart, out + 8388608);
    k6_moe<<<2048, 256, 0, stream>>>(xo, ln2g, ln2b, wg, w1t, b1, w2t, b2,
                                     xre, xim, out);
}

// Round 21
// 185.316 us; speedup vs baseline: 1.4630x; 1.0241x over previous
//
#include <hip/hip_runtime.h>
#include <math.h>

#define PX 4096   // 64*64
#define TT 32
#define DD 32
#define CC 64     // 2*D
#define PW 66     // padded width
#define PPX 4356  // 66*66

typedef __attribute__((ext_vector_type(8))) short short8v;
typedef __attribute__((ext_vector_type(4))) float f32x4;

__device__ __forceinline__ float gelu_fast(float x) {
    float u = x * x;
    float a = x * (1.5957691216057308f + 0.07135481627f * u);
    return x / (1.0f + __expf(-a));
}

__device__ __forceinline__ unsigned short f2b(float x) {
    union { float f; unsigned u; } v; v.f = x;
    unsigned r = v.u + 0x7FFF + ((v.u >> 16) & 1);
    return (unsigned short)(r >> 16);
}

__device__ __forceinline__ float b2f(unsigned short b) {
    union { unsigned u; float f; } v; v.u = ((unsigned)b) << 16;
    return v.f;
}

// ---------------- K1: LN1 (64ch) fused -> padded bf16 NHWC ------------------
__global__ __launch_bounds__(256) void k1_ln1(
        const float* __restrict__ xre, const float* __restrict__ xim,
        const float* __restrict__ g, const float* __restrict__ b,
        unsigned short* __restrict__ xpad) {
    int gid = blockIdx.x * 256 + threadIdx.x;   // t*4096 + px
    int t = gid >> 12, px = gid & 4095;
    int row = px >> 6, col = px & 63;
    const float* pr = xre + (size_t)t * DD * PX + px;
    const float* pi = xim + (size_t)t * DD * PX + px;
    float s = 0.f, ss = 0.f;
    #pragma unroll
    for (int d = 0; d < DD; ++d) {
        float vr = pr[d * PX], vi = pi[d * PX];
        s += vr + vi; ss += vr * vr + vi * vi;
    }
    float m = s * (1.f / 64.f);
    float var = ss * (1.f / 64.f) - m * m;
    float rs = rsqrtf(var + 1e-5f);
    unsigned short* o = xpad + ((size_t)t * PPX + (row + 1) * PW + (col + 1)) * 64;
    #pragma unroll
    for (int j = 0; j < 8; ++j) {
        short8v v8;
        #pragma unroll
        for (int dd = 0; dd < 8; ++dd) {
            int ch = j * 8 + dd;
            float v = (ch < 32) ? (pr[ch * PX] - m) * rs * g[ch] + b[ch]
                                : (pi[(ch - 32) * PX] - m) * rs * g[ch] + b[ch];
            v8[dd] = (short)f2b(v);
        }
        *(short8v*)&o[j * 8] = v8;
    }
}

// ------- K0: prep — weights bf16/transpose/swizzle + xpad halo + tabs -------
__global__ __launch_bounds__(256) void k0_prep(
        const float* __restrict__ w1, const float* __restrict__ w2,
        const float* __restrict__ convw,
        const float* __restrict__ encre, const float* __restrict__ encim,
        const float* __restrict__ decre, const float* __restrict__ decim,
        const float* __restrict__ dt, const float* __restrict__ lam_re,
        const float* __restrict__ lam_im,
        unsigned short* __restrict__ w1t, unsigned short* __restrict__ w2t,
        unsigned short* __restrict__ w9t,
        unsigned short* __restrict__ benct, unsigned short* __restrict__ bdect,
        unsigned short* __restrict__ xpad, float* __restrict__ tabs) {
    int gid = blockIdx.x * 256 + threadIdx.x;
    if (gid < 32768) {
        int idx = gid;
        int e = idx >> 13, r = idx & 8191;
        int f = r >> 6, p = r & 63;
        int c = (p & 7) + 8 * ((p >> 3) ^ (f & 7));
        w1t[idx] = f2b(w1[((size_t)e * 64 + c) * 128 + f]);
    } else if (gid < 65536) {
        int idx = gid - 32768;
        int e = idx >> 13, r = idx & 8191;
        int n = r >> 7, p = r & 127;
        int f = (p & 7) + 8 * ((p >> 3) ^ (n & 7));
        w2t[idx] = f2b(w2[((size_t)e * 128 + f) * 64 + n]);
    } else if (gid < 102400) {
        int idx = gid - 65536;
        int tap = idx >> 12, rem = idx & 4095;
        int n = rem >> 6, p = rem & 63;
        int k = (p & 7) + 8 * ((p >> 3) ^ (n & 7));
        w9t[idx] = f2b(convw[((size_t)n * 64 + k) * 9 + tap]);
    } else if (gid < 110592) {
        int idx = gid - 102400;
        const float* Rr = (idx < 4096) ? encre : decre;
        const float* Ri = (idx < 4096) ? encim : decim;
        unsigned short* dst = (idx < 4096) ? benct : bdect;
        idx &= 4095;
        int n = idx >> 6, p = idx & 63;
        int k = (p & 7) + 8 * ((p >> 3) ^ (n & 7));
        float v;
        if (n < 32) v = (k < 32) ? Rr[k * 32 + n] : -Ri[(k - 32) * 32 + n];
        else        v = (k < 32) ? Ri[k * 32 + (n - 32)] : Rr[(k - 32) * 32 + (n - 32)];
        dst[idx] = f2b(v);
    } else if (gid < 118912) {
        int idx = gid - 110592;                 // halo zeroing
        int im = idx / 260, h = idx % 260;
        int row, col;
        if (h < 66)       { row = 0;  col = h; }
        else if (h < 132) { row = 65; col = h - 66; }
        else { int hh = h - 132; row = 1 + (hh >> 1); col = (hh & 1) * 65; }
        unsigned short* p = xpad + ((size_t)im * PPX + row * PW + col) * 64;
        short8v z = (short8v)0;
        #pragma unroll
        for (int j = 0; j < 8; ++j) *(short8v*)&p[j * 8] = z;
    } else if (gid < 119936) {
        int idx = gid - 118912;                 // tabs (decay/forcing)
        int t = idx >> 5, d = idx & 31;
        float x = lam_re[d];
        float sp = (x > 0.f) ? x + log1pf(expf(-x)) : log1pf(expf(x));
        float lr = -sp, li = lam_im[d];
        float dtv = dt[t];
        float er = expf(lr * dtv);
        float dr = er * cosf(li * dtv);
        float di = er * sinf(li * dtv);
        float den = lr * lr + li * li;
        float fr = ((dr - 1.f) * lr + di * li) / den;
        float fi = (di * lr - (dr - 1.f) * li) / den;
        tabs[idx] = dr; tabs[1024 + idx] = di;
        tabs[2048 + idx] = fr; tabs[3072 + idx] = fi;
    }
}

// ---------------- K2: 3x3 conv 64->64 as 9-tap implicit GEMM (bf16 MFMA) ----
__global__ __launch_bounds__(256, 2) void k2_conv(
        const unsigned short* __restrict__ xpad,
        const unsigned short* __restrict__ w9t,
        const float* __restrict__ bias, float* __restrict__ xs) {
    __shared__ __align__(16) unsigned short wst[36864];   // 9 taps x 64oc x 64ic swz
    int tid = threadIdx.x;
    int bid = blockIdx.x;
    int lb = (bid & 7) * 64 + (bid >> 3);   // bijective (512 % 8 == 0)
    int t = lb >> 4, rg = lb & 15;
    int lane = tid & 63, wv = tid >> 6;
    int l15 = lane & 15, g = lane >> 4;
    #pragma unroll
    for (int i = 0; i < 18; ++i) {
        int idx = i * 256 + tid;
        *(short8v*)&wst[idx * 8] = *(const short8v*)&w9t[idx * 8];
    }
    __syncthreads();
    int r = rg * 4 + wv;
    const unsigned short* xb = xpad + (size_t)t * PPX * 64;
    f32x4 acc[4][4];
    #pragma unroll
    for (int m = 0; m < 4; ++m)
        #pragma unroll
        for (int nt = 0; nt < 4; ++nt) acc[m][nt] = (f32x4)0.f;

    #pragma unroll
    for (int kh = 0; kh < 3; ++kh) {
        #pragma unroll
        for (int kw = 0; kw < 3; ++kw) {
            int tap = kh * 3 + kw;
            #pragma unroll
            for (int kc = 0; kc < 2; ++kc) {
                short8v a[4];
                #pragma unroll
                for (int m = 0; m < 4; ++m) {
                    int pcol = m * 16 + l15 + kw;
                    a[m] = *(const short8v*)&xb[((size_t)(r + kh) * PW + pcol) * 64 + kc * 32 + g * 8];
                }
                #pragma unroll
                for (int nt = 0; nt < 4; ++nt) {
                    int n = nt * 16 + l15;
                    short8v bf = *(const short8v*)&wst[tap * 4096 + n * 64 + ((kc * 4 + g) ^ (n & 7)) * 8];
                    #pragma unroll
                    for (int m = 0; m < 4; ++m)
                        acc[m][nt] = __builtin_amdgcn_mfma_f32_16x16x32_bf16(a[m], bf, acc[m][nt], 0, 0, 0);
                }
            }
        }
    }
    float* dst = xs + ((size_t)t * PX + r * 64) * 64;
    #pragma unroll
    for (int nt = 0; nt < 4; ++nt) {
        float bo = bias[nt * 16 + l15];
        #pragma unroll
        for (int m = 0; m < 4; ++m) {
            #pragma unroll
            for (int reg = 0; reg < 4; ++reg) {
                int tok = m * 16 + g * 4 + reg;
                dst[(size_t)tok * 64 + nt * 16 + l15] = acc[m][nt][reg] + bo;
            }
        }
    }
}

// ---------------- K5a/K5c: token GEMM, 2 tiles (128 tok) per block ----------
// FORCING variant also accumulates per-channel partial sums of A into mpart.
template<bool FORCING>
__global__ __launch_bounds__(256) void k5_gemm(
        const float* A, const unsigned short* __restrict__ Bt,
        const float* __restrict__ tabs, float* O, float* __restrict__ mpart) {
    __shared__ __align__(16) unsigned short fA[64 * 64];
    __shared__ __align__(16) unsigned short bst[64 * 64];
    __shared__ float red[256];
    int tid = threadIdx.x;
    int lane = tid & 63, wv = tid >> 6;
    int l15 = lane & 15, g = lane >> 4;
    int row0 = wv * 16 + l15;
    int rowb = wv * 16 + g * 4;
    #pragma unroll
    for (int i = 0; i < 2; ++i)
        *(short8v*)&bst[(i * 256 + tid) * 8] = *(const short8v*)&Bt[(i * 256 + tid) * 8];

    float msum = 0.f;
    #pragma unroll
    for (int tile = 0; tile < 2; ++tile) {
        size_t tok0 = ((size_t)blockIdx.x * 2 + tile) * 64;
        if (tile) __syncthreads();   // prev tile's fA fragment reads done
        #pragma unroll
        for (int r = 0; r < 16; ++r) {
            int idx = r * 256 + tid;
            int tok = idx >> 6, c = idx & 63;
            float v = A[(tok0 + tok) * 64 + c];
            if (FORCING) msum += v;
            fA[tok * 64 + (c & 7) + 8 * ((c >> 3) ^ (tok & 7))] = f2b(v);
        }
        __syncthreads();   // fA (+bst on tile 0) ready
        short8v a1[2];
        #pragma unroll
        for (int st = 0; st < 2; ++st)
            a1[st] = *(const short8v*)&fA[row0 * 64 + (((st * 4 + g) ^ (row0 & 7))) * 8];
        f32x4 eo[4];
        #pragma unroll
        for (int i = 0; i < 4; ++i) eo[i] = (f32x4)0.f;
        #pragma unroll
        for (int st = 0; st < 2; ++st) {
            #pragma unroll
            for (int nt = 0; nt < 4; ++nt) {
                int n = nt * 16 + l15;
                short8v b = *(const short8v*)&bst[n * 64 + (((st * 4 + g) ^ (n & 7))) * 8];
                eo[nt] = __builtin_amdgcn_mfma_f32_16x16x32_bf16(a1[st], b, eo[nt], 0, 0, 0);
            }
        }
        if (FORCING) {
            int t = (int)(tok0 >> 12);
            #pragma unroll
            for (int p = 0; p < 2; ++p) {
                int d = p * 16 + l15;
                float fr = tabs[2048 + t * 32 + d], fi = tabs[3072 + t * 32 + d];
                #pragma unroll
                for (int r = 0; r < 4; ++r) {
                    float ur = eo[p][r], ui = eo[p + 2][r];
                    eo[p][r]     = ur * fr - ui * fi;
                    eo[p + 2][r] = ur * fi + ui * fr;
                }
            }
        }
        #pragma unroll
        for (int nt = 0; nt < 4; ++nt) {
            int n = nt * 16 + l15;
            #pragma unroll
            for (int r = 0; r < 4; ++r)
                O[(tok0 + rowb + r) * 64 + n] = eo[nt][r];
        }
    }
    if (FORCING) {
        __syncthreads();          // fA reads done; reuse red
        red[tid] = msum;
        __syncthreads();
        if (tid < 64)
            mpart[(size_t)blockIdx.x * 64 + tid] =
                red[tid] + red[tid + 64] + red[tid + 128] + red[tid + 192];
    }
}

// --------- K5b: time scan + noise (in-place) + flux tail on block 0 ---------
__global__ __launch_bounds__(256) void k5b_scan(
        float* U, const float* __restrict__ tabs, const float* __restrict__ dt,
        const float* __restrict__ eps_re, const float* __restrict__ eps_im,
        const float* __restrict__ alpha,
        const float* __restrict__ wre, const float* __restrict__ wim,
        const float* __restrict__ mpart, float* __restrict__ outflux) {
    __shared__ float meanl[2048];
    int tid = threadIdx.x;
    int gid = blockIdx.x * 256 + tid;   // px*32 + d
    int px = gid >> 5, d = gid & 31;
    float Yr = 0.f, Yi = 0.f;
    for (int t = 0; t < TT; ++t) {
        size_t tok = (size_t)t * PX + px;
        float usr = U[tok * 64 + d], usi = U[tok * 64 + 32 + d];
        float dr = tabs[t * 32 + d], di = tabs[1024 + t * 32 + d];
        float nYr = dr * Yr - di * Yi + usr;
        float nYi = dr * Yi + di * Yr + usi;
        Yr = nYr; Yi = nYi;
        float s = 0.01f * sqrtf(dt[t]);
        size_t ei = tok * 32 + d;
        float epr = eps_re[ei], epi = eps_im[ei];
        U[tok * 64 + d]      = Yr + s * (Yr * epr - Yi * epi);
        U[tok * 64 + 32 + d] = Yi + s * (Yr * epi + Yi * epr);
    }
    // flux tail (was k4_flux): mpart complete before this kernel launched
    if (blockIdx.x == 0) {
        for (int idx = tid; idx < 2048; idx += 256) {
            int t = idx >> 6, c = idx & 63;
            float s = 0.f;
            #pragma unroll
            for (int p = 0; p < 32; ++p) s += mpart[((size_t)t * 32 + p) * 64 + c];
            meanl[idx] = s * (1.f / 4096.f);
        }
        __syncthreads();
        if (tid < 32) {
            int dd = tid;
            float a = 1.f / (1.f + expf(-alpha[dd]));
            float yr = 0.f, yi = 0.f;
            for (int t = 0; t < 32; ++t) {
                float xr = 0.f, xi = 0.f;
                for (int k = 0; k < 32; ++k) {
                    float mr = meanl[t * 64 + k], mi = meanl[t * 64 + 32 + k];
                    float wr = wre[k * 32 + dd], wi = wim[k * 32 + dd];
                    xr += mr * wr - mi * wi;
                    xi += mr * wi + mi * wr;
                }
                yr = a * yr + xr; yi = a * yi + xi;
            }
            outflux[dd] = yr; outflux[32 + dd] = yi;
        }
    }
}

// ---------------- K6: LN2 + gated MoE MLP — R9/R14-proven (96 µs) -----------
__global__ __launch_bounds__(256, 4) void k6_moe(
        const float* __restrict__ xo,
        const float* __restrict__ g2, const float* __restrict__ b2ln,
        const float* __restrict__ wg,
        const unsigned short* __restrict__ w1t, const float* __restrict__ b1,
        const unsigned short* __restrict__ w2t, const float* __restrict__ b2m,
        const float* __restrict__ xre, const float* __restrict__ xim,
        float* __restrict__ out) {
    __shared__ __align__(16) float hdl[64 * 65];           // H bf16[64][128] / delta f32[64][65]
    __shared__ __align__(16) unsigned short wst[8192];     // one weight matrix
    __shared__ float wgl[256];
    unsigned short* H = (unsigned short*)hdl;

    int tid = threadIdx.x;
    int lane = tid & 63;
    int wv = tid >> 6;
    int l15 = lane & 15, g = lane >> 4;
    int t = blockIdx.x >> 6;
    int px0 = (blockIdx.x & 63) * 64;
    int tok = wv * 16 + l15;
    int tsw = tok & 7;

    wgl[tid] = wg[tid];

    float f[16];
    {
        const float* src = xo + ((size_t)t * PX + px0 + tok) * 64 + g * 8;
        #pragma unroll
        for (int st = 0; st < 2; ++st) {
            float4 v0 = *(const float4*)&src[st * 32];
            float4 v1 = *(const float4*)&src[st * 32 + 4];
            f[st*8+0]=v0.x; f[st*8+1]=v0.y; f[st*8+2]=v0.z; f[st*8+3]=v0.w;
            f[st*8+4]=v1.x; f[st*8+5]=v1.y; f[st*8+6]=v1.z; f[st*8+7]=v1.w;
        }
    }
    float s = 0.f, ss = 0.f;
    #pragma unroll
    for (int i = 0; i < 16; ++i) { s += f[i]; ss += f[i] * f[i]; }
    s += __shfl_xor(s, 16); ss += __shfl_xor(ss, 16);
    s += __shfl_xor(s, 32); ss += __shfl_xor(ss, 32);
    float m = s * (1.f / 64.f);
    float rs = rsqrtf(ss * (1.f / 64.f) - m * m + 1e-5f);
    #pragma unroll
    for (int st = 0; st < 2; ++st) {
        int c0 = st * 32 + g * 8;
        float4 gv0 = *(const float4*)&g2[c0],   gv1 = *(const float4*)&g2[c0 + 4];
        float4 bv0 = *(const float4*)&b2ln[c0], bv1 = *(const float4*)&b2ln[c0 + 4];
        f[st*8+0] = (f[st*8+0]-m)*rs*gv0.x + bv0.x;
        f[st*8+1] = (f[st*8+1]-m)*rs*gv0.y + bv0.y;
        f[st*8+2] = (f[st*8+2]-m)*rs*gv0.z + bv0.z;
        f[st*8+3] = (f[st*8+3]-m)*rs*gv0.w + bv0.w;
        f[st*8+4] = (f[st*8+4]-m)*rs*gv1.x + bv1.x;
        f[st*8+5] = (f[st*8+5]-m)*rs*gv1.y + bv1.y;
        f[st*8+6] = (f[st*8+6]-m)*rs*gv1.z + bv1.z;
        f[st*8+7] = (f[st*8+7]-m)*rs*gv1.w + bv1.w;
    }
    __syncthreads();   // wgl visible
    float gt[4];
    {
        float g0 = 0.f, g1 = 0.f, g2_ = 0.f, g3 = 0.f;
        #pragma unroll
        for (int st = 0; st < 2; ++st)
            #pragma unroll
            for (int j = 0; j < 8; ++j) {
                int c = st * 32 + g * 8 + j;
                float fv = f[st * 8 + j];
                float4 w4 = *(const float4*)&wgl[c * 4];
                g0 += fv * w4.x; g1 += fv * w4.y;
                g2_ += fv * w4.z; g3 += fv * w4.w;
            }
        g0 += __shfl_xor(g0, 16); g1 += __shfl_xor(g1, 16);
        g2_ += __shfl_xor(g2_, 16); g3 += __shfl_xor(g3, 16);
        g0 += __shfl_xor(g0, 32); g1 += __shfl_xor(g1, 32);
        g2_ += __shfl_xor(g2_, 32); g3 += __shfl_xor(g3, 32);
        float mx = fmaxf(fmaxf(g0, g1), fmaxf(g2_, g3));
        float e0 = expf(g0-mx), e1 = expf(g1-mx), e2 = expf(g2_-mx), e3 = expf(g3-mx);
        float inv = 1.f / (e0 + e1 + e2 + e3);
        gt[0] = e0*inv; gt[1] = e1*inv; gt[2] = e2*inv; gt[3] = e3*inv;
    }
    short8v bf1[2];
    #pragma unroll
    for (int st = 0; st < 2; ++st)
        #pragma unroll
        for (int j = 0; j < 8; ++j)
            bf1[st][j] = (short)f2b(f[st * 8 + j]);

    f32x4 dacc[4];
    #pragma unroll
    for (int i = 0; i < 4; ++i) dacc[i] = (f32x4)0.f;

    for (int e = 0; e < 4; ++e) {
        __syncthreads();   // prev GEMM2 done reading wst/H
        {
            const short8v* gp = (const short8v*)(w1t + (size_t)e * 8192);
            #pragma unroll
            for (int i = 0; i < 4; ++i)
                *(short8v*)&wst[(i * 256 + tid) * 8] = gp[i * 256 + tid];
        }
        __syncthreads();   // w1e ready
        f32x4 h[8];
        #pragma unroll
        for (int i = 0; i < 8; ++i) h[i] = (f32x4)0.f;
        #pragma unroll
        for (int st = 0; st < 2; ++st) {
            #pragma unroll
            for (int ft = 0; ft < 8; ++ft) {
                int fi = ft * 16 + l15;
                short8v a = *(const short8v*)&wst[fi * 64 + (((st * 4 + g) ^ (fi & 7))) * 8];
                h[ft] = __builtin_amdgcn_mfma_f32_16x16x32_bf16(a, bf1[st], h[ft], 0, 0, 0);
            }
        }
        #pragma unroll
        for (int ft = 0; ft < 8; ++ft) {
            int f0 = ft * 16 + g * 4;
            float4 bb = *(const float4*)&b1[e * 128 + f0];
            unsigned short p0 = f2b(gelu_fast(h[ft][0] + bb.x));
            unsigned short p1 = f2b(gelu_fast(h[ft][1] + bb.y));
            unsigned short p2 = f2b(gelu_fast(h[ft][2] + bb.z));
            unsigned short p3 = f2b(gelu_fast(h[ft][3] + bb.w));
            unsigned long long pk = (unsigned long long)p0 | ((unsigned long long)p1 << 16)
                                  | ((unsigned long long)p2 << 32) | ((unsigned long long)p3 << 48);
            *(unsigned long long*)&H[tok * 128 + (f0 & 7) + 8 * ((f0 >> 3) ^ tsw)] = pk;
        }
        __syncthreads();   // GEMM1 wst reads done + H complete
        {
            const short8v* gp = (const short8v*)(w2t + (size_t)e * 8192);
            #pragma unroll
            for (int i = 0; i < 4; ++i)
                *(short8v*)&wst[(i * 256 + tid) * 8] = gp[i * 256 + tid];
        }
        __syncthreads();   // w2e ready
        f32x4 eo[4];
        #pragma unroll
        for (int i = 0; i < 4; ++i) eo[i] = (f32x4)0.f;
        #pragma unroll
        for (int st = 0; st < 4; ++st) {
            short8v bh = *(const short8v*)&H[tok * 128 + (((st * 4 + g) ^ tsw)) * 8];
            #pragma unroll
            for (int nt = 0; nt < 4; ++nt) {
                int n = nt * 16 + l15;
                short8v a = *(const short8v*)&wst[n * 128 + (((st * 4 + g) ^ (n & 7))) * 8];
                eo[nt] = __builtin_amdgcn_mfma_f32_16x16x32_bf16(a, bh, eo[nt], 0, 0, 0);
            }
        }
        float ge = gt[e];
        #pragma unroll
        for (int nt = 0; nt < 4; ++nt) {
            int n0 = nt * 16 + g * 4;
            float4 bb = *(const float4*)&b2m[e * 64 + n0];
            dacc[nt][0] += ge * (eo[nt][0] + bb.x);
            dacc[nt][1] += ge * (eo[nt][1] + bb.y);
            dacc[nt][2] += ge * (eo[nt][2] + bb.z);
            dacc[nt][3] += ge * (eo[nt][3] + bb.w);
        }
    }
    __syncthreads();   // all H reads done; reuse hdl as f32 delta [64][65]
    float* dl = hdl;
    #pragma unroll
    for (int nt = 0; nt < 4; ++nt) {
        int n0 = nt * 16 + g * 4;
        #pragma unroll
        for (int r = 0; r < 4; ++r)
            dl[tok * 65 + n0 + r] = dacc[nt][r];
    }
    __syncthreads();
    #pragma unroll
    for (int st = 0; st < 2; ++st) {
        const float* xsrc = (st == 0) ? xre : xim;
        float* osrc = out + (st == 0 ? 0 : (size_t)4194304);
        #pragma unroll
        for (int j = 0; j < 8; ++j) {
            int c = st * 32 + g * 8 + j;
            float val = b2f((unsigned short)bf1[st][j]) + dl[tok * 65 + c];
            size_t xi_ = ((size_t)t * 32 + (c & 31)) * PX + px0 + tok;
            osrc[xi_] = val + xsrc[xi_];
        }
    }
}

extern "C" void kernel_launch(void* const* d_in, const int* in_sizes, int n_in,
                              void* d_out, int out_size, void* d_ws, size_t ws_size,
                              hipStream_t stream) {
    const float* xre   = (const float*)d_in[0];
    const float* xim   = (const float*)d_in[1];
    const float* dt    = (const float*)d_in[2];
    const float* epsre = (const float*)d_in[3];
    const float* epsim = (const float*)d_in[4];
    const float* ln1g  = (const float*)d_in[5];
    const float* ln1b  = (const float*)d_in[6];
    const float* ln2g  = (const float*)d_in[7];
    const float* ln2b  = (const float*)d_in[8];
    const float* convw = (const float*)d_in[9];
    const float* convb = (const float*)d_in[10];
    const float* encre = (const float*)d_in[11];
    const float* encim = (const float*)d_in[12];
    const float* decre = (const float*)d_in[13];
    const float* decim = (const float*)d_in[14];
    const float* lamre = (const float*)d_in[15];
    const float* lamim = (const float*)d_in[16];
    const float* alpha = (const float*)d_in[17];
    const float* fwre  = (const float*)d_in[18];
    const float* fwim  = (const float*)d_in[19];
    const float* wg    = (const float*)d_in[20];
    const float* w1    = (const float*)d_in[21];
    const float* b1    = (const float*)d_in[22];
    const float* w2    = (const float*)d_in[23];
    const float* b2    = (const float*)d_in[24];
    float* out = (float*)d_out;

    float* ws = (float*)d_ws;
    unsigned short* xpad = (unsigned short*)ws;   // region A: xpad bf16 then xo f32
    float* xo   = ws;
    float* xs   = ws + 8388608;         // NHWC f32: conv out -> U (in-place) -> W
    float* tabs = ws + 16779264;        // 4096 floats
    unsigned short* w1t = (unsigned short*)(ws + 16783360);
    unsigned short* w2t = w1t + 32768;
    unsigned short* w9t = w2t + 32768;
    unsigned short* benct = w9t + 36864;
    unsigned short* bdect = benct + 4096;
    float* mpart = ws + 16783360 + 55296;   // 1024*64 floats

    k0_prep<<<469, 256, 0, stream>>>(w1, w2, convw, encre, encim, decre, decim,
                                     dt, lamre, lamim,
                                     w1t, w2t, w9t, benct, bdect, xpad, tabs);
    k1_ln1<<<512, 256, 0, stream>>>(xre, xim, ln1g, ln1b, xpad);
    k2_conv<<<512, 256, 0, stream>>>(xpad, w9t, convb, xs);
    k5_gemm<true><<<1024, 256, 0, stream>>>(xs, benct, tabs, xs, mpart);   // enc+forcing+mean
    k5b_scan<<<512, 256, 0, stream>>>(xs, tabs, dt, epsre, epsim,
                                      alpha, fwre, fwim, mpart, out + 8388608);
    k5_gemm<false><<<1024, 256, 0, stream>>>(xs, bdect, tabs, xo, nullptr);// dec
    k6_moe<<<2048, 256, 0, stream>>>(xo, ln2g, ln2b, wg, w1t, b1, w2t, b2,
                                     xre, xim, out);
}